// Round 1
// baseline (624.806 us; speedup 1.0000x reference)
//
#include <hip/hip_runtime.h>

#define SEQ  3072
#define HID  1280
#define NH   16
#define HD   80
#define HDP  96
#define NQKV 3840

typedef unsigned short u16;
typedef __attribute__((ext_vector_type(8))) short short8;
typedef __attribute__((ext_vector_type(4))) float floatx4;

__device__ __forceinline__ u16 f2bf(float x) {
    unsigned int u = __float_as_uint(x);
    u += 0x7fffu + ((u >> 16) & 1u);
    return (u16)(u >> 16);
}
__device__ __forceinline__ float bf2f(u16 b) {
    return __uint_as_float(((unsigned int)b) << 16);
}

// ---------------- rope tables: cos/sin [SEQ][40] ----------------
__global__ void rope_tables_k(const int* __restrict__ pos, float* __restrict__ cosb,
                              float* __restrict__ sinb) {
    int s = blockIdx.x;
    int j = threadIdx.x;
    if (j >= 40) return;
    float p = (float)((j < 20) ? pos[s * 2] : pos[s * 2 + 1]);
    int i = (j < 20) ? j : j - 20;
    float inv = powf(10000.0f, -(float)i / 20.0f);
    float a = p * inv;
    cosb[s * 40 + j] = cosf(a);
    sinb[s * 40 + j] = sinf(a);
}

// ---------------- split f32 -> bf16 hi/lo ----------------
__global__ void split_bf16_k(const float* __restrict__ x, u16* __restrict__ hi,
                             u16* __restrict__ lo, int n) {
    int i = blockIdx.x * 256 + threadIdx.x;
    if (i >= n) return;
    float v = x[i];
    u16 h = f2bf(v);
    hi[i] = h;
    lo[i] = f2bf(v - bf2f(h));
}

// ---------------- transpose + split: w[K][N] -> t[N][K] hi/lo ----------------
__global__ void transpose_split_k(const float* __restrict__ w, u16* __restrict__ thi,
                                  u16* __restrict__ tlo, int K, int N) {
    __shared__ float tile[32][33];
    int n0 = blockIdx.x * 32, k0 = blockIdx.y * 32;
    int c = threadIdx.x & 31, r8 = threadIdx.x >> 5;
    for (int rr = r8; rr < 32; rr += 8)
        tile[rr][c] = w[(size_t)(k0 + rr) * N + n0 + c];
    __syncthreads();
    for (int rr = r8; rr < 32; rr += 8) {
        float x = tile[c][rr];           // = w[k0+c][n0+rr]
        u16 h = f2bf(x);
        size_t o = (size_t)(n0 + rr) * K + k0 + c;
        thi[o] = h;
        tlo[o] = f2bf(x - bf2f(h));
    }
}

// ---------------- split GEMM: C[M][N] = A[M][K] * Bt[N][K]^T + bias ----------------
// A,Bt given as bf16 hi/lo. 3-product split: ah*bh + ah*bl + al*bh.
#define LP 40   // LDS pitch (elems) for 32-wide K tiles: 80B rows, 16B aligned, 2-way banks
__global__ __launch_bounds__(256, 2) void gemm_split_k(
    const u16* __restrict__ Ahi, const u16* __restrict__ Alo,
    const u16* __restrict__ Bhi, const u16* __restrict__ Blo,
    const float* __restrict__ bias, float* __restrict__ C,
    int M, int N, int K) {
    __shared__ u16 lA[2][128 * LP];
    __shared__ u16 lB[2][128 * LP];
    const int t = threadIdx.x, lane = t & 63, w = t >> 6;
    const int m0 = blockIdx.y * 128, n0 = blockIdx.x * 128;
    const int wm = (w >> 1) * 64, wn = (w & 1) * 64;

    floatx4 acc[4][4];
    for (int mi = 0; mi < 4; mi++)
        for (int ni = 0; ni < 4; ni++) acc[mi][ni] = (floatx4){0.f, 0.f, 0.f, 0.f};

    for (int k0 = 0; k0 < K; k0 += 32) {
        for (int i = t; i < 512; i += 256) {
            int row = i >> 2, blk = i & 3;
            size_t ga = (size_t)(m0 + row) * K + k0 + blk * 8;
            size_t gb = (size_t)(n0 + row) * K + k0 + blk * 8;
            int lo = row * LP + blk * 8;
            *(uint4*)&lA[0][lo] = *(const uint4*)&Ahi[ga];
            *(uint4*)&lA[1][lo] = *(const uint4*)&Alo[ga];
            *(uint4*)&lB[0][lo] = *(const uint4*)&Bhi[gb];
            *(uint4*)&lB[1][lo] = *(const uint4*)&Blo[gb];
        }
        __syncthreads();
        short8 ah[4], al[4], bh[4], bl[4];
        for (int mi = 0; mi < 4; mi++) {
            int off = (wm + mi * 16 + (lane & 15)) * LP + (lane >> 4) * 8;
            ah[mi] = *(const short8*)&lA[0][off];
            al[mi] = *(const short8*)&lA[1][off];
        }
        for (int ni = 0; ni < 4; ni++) {
            int off = (wn + ni * 16 + (lane & 15)) * LP + (lane >> 4) * 8;
            bh[ni] = *(const short8*)&lB[0][off];
            bl[ni] = *(const short8*)&lB[1][off];
        }
        for (int mi = 0; mi < 4; mi++)
            for (int ni = 0; ni < 4; ni++) {
                acc[mi][ni] = __builtin_amdgcn_mfma_f32_16x16x32_bf16(ah[mi], bh[ni], acc[mi][ni], 0, 0, 0);
                acc[mi][ni] = __builtin_amdgcn_mfma_f32_16x16x32_bf16(ah[mi], bl[ni], acc[mi][ni], 0, 0, 0);
                acc[mi][ni] = __builtin_amdgcn_mfma_f32_16x16x32_bf16(al[mi], bh[ni], acc[mi][ni], 0, 0, 0);
            }
        __syncthreads();
    }
    for (int mi = 0; mi < 4; mi++)
        for (int ni = 0; ni < 4; ni++) {
            int col = n0 + wn + ni * 16 + (lane & 15);
            int rowb = m0 + wm + mi * 16 + (lane >> 4) * 4;
            float b = bias[col];
            for (int r = 0; r < 4; r++)
                C[(size_t)(rowb + r) * N + col] = acc[mi][ni][r] + b;
        }
}

// ---------------- pack: rope+scale Q,K -> [h][s][96]; V -> Vt[h][80][SEQ] hi/lo ----------------
__global__ void pack_qkv_k(const float* __restrict__ qkv, const float* __restrict__ cosb,
                           const float* __restrict__ sinb,
                           u16* __restrict__ Qhi, u16* __restrict__ Qlo, u16* __restrict__ Khi,
                           u16* __restrict__ Vthi, u16* __restrict__ Vtlo) {
    __shared__ float lv[80 * 65];
    const int t = threadIdx.x;
    const int h = blockIdx.y, s0 = blockIdx.x * 64;
    const float scale = 0.11180339887498949f;  // 80^-0.5

    for (int i = t; i < 64 * 40; i += 256) {
        int rl = i / 40, j = i % 40;
        int s = s0 + rl;
        float c = cosb[s * 40 + j], sn = sinb[s * 40 + j];
        const float* qb = qkv + (size_t)s * NQKV + h * HD;
        float q1 = qb[j], q2 = qb[j + 40];
        float o1 = (q1 * c - q2 * sn) * scale;
        float o2 = (q2 * c + q1 * sn) * scale;
        size_t qo = (size_t)(h * SEQ + s) * HDP;
        u16 h1 = f2bf(o1), h2 = f2bf(o2);
        Qhi[qo + j] = h1;
        Qhi[qo + j + 40] = h2;
        Qlo[qo + j] = f2bf(o1 - bf2f(h1));
        Qlo[qo + j + 40] = f2bf(o2 - bf2f(h2));
        const float* kb = qb + HID;
        float k1 = kb[j], k2 = kb[j + 40];
        Khi[qo + j] = f2bf(k1 * c - k2 * sn);
        Khi[qo + j + 40] = f2bf(k2 * c + k1 * sn);
    }
    for (int i = t; i < 64 * 16; i += 256) {  // zero pad cols 80..95
        int rl = i / 16, pc = i % 16;
        size_t qo = (size_t)(h * SEQ + s0 + rl) * HDP + 80 + pc;
        Qhi[qo] = 0; Qlo[qo] = 0; Khi[qo] = 0;
    }
    for (int i = t; i < 64 * 80; i += 256) {
        int rl = i / 80, d = i % 80;
        lv[d * 65 + rl] = qkv[(size_t)(s0 + rl) * NQKV + 2 * HID + h * HD + d];
    }
    __syncthreads();
    for (int i = t; i < 80 * 64; i += 256) {
        int d = i / 64, c2 = i % 64;
        float v = lv[d * 65 + c2];
        u16 hi = f2bf(v);
        size_t vo = ((size_t)h * HD + d) * SEQ + s0 + c2;
        Vthi[vo] = hi;
        Vtlo[vo] = f2bf(v - bf2f(hi));
    }
}

// ---------------- flash attention ----------------
// block: 64 q-rows (16/wave), iterate 64-wide K/V tiles, online softmax.
__global__ __launch_bounds__(256, 2) void attn_k(
    const u16* __restrict__ Qhi, const u16* __restrict__ Qlo, const u16* __restrict__ Khi,
    const u16* __restrict__ Vthi, const u16* __restrict__ Vtlo,
    u16* __restrict__ atthi, u16* __restrict__ attlo) {
    __shared__ u16 qth[64 * 104];
    __shared__ u16 qtl[64 * 104];
    __shared__ u16 kts[64 * 104];
    __shared__ u16 vth[80 * 72];
    __shared__ u16 vtl[80 * 72];
    __shared__ u16 pls[64 * 72];

    const int t = threadIdx.x, lane = t & 63, w = t >> 6;
    const int h = blockIdx.y, q0 = blockIdx.x * 64;

    const u16* Qhb = Qhi + (size_t)(h * SEQ + q0) * HDP;
    const u16* Qlb = Qlo + (size_t)(h * SEQ + q0) * HDP;
    for (int i = t; i < 64 * 12; i += 256) {
        int row = i / 12, blk = i % 12;
        *(uint4*)&qth[row * 104 + blk * 8] = *(const uint4*)&Qhb[row * HDP + blk * 8];
        *(uint4*)&qtl[row * 104 + blk * 8] = *(const uint4*)&Qlb[row * HDP + blk * 8];
    }
    __syncthreads();
    short8 aqh[3], aql[3];
    {
        int rb = (w * 16 + (lane & 15)) * 104 + (lane >> 4) * 8;
        aqh[0] = *(const short8*)&qth[rb];
        aqh[1] = *(const short8*)&qth[rb + 32];
        aqh[2] = *(const short8*)&qth[rb + 64];
        aql[0] = *(const short8*)&qtl[rb];
        aql[1] = *(const short8*)&qtl[rb + 32];
        aql[2] = *(const short8*)&qtl[rb + 64];
    }

    float m_r[4], l_r[4];
    floatx4 acco[5];
    for (int r = 0; r < 4; r++) { m_r[r] = -1e30f; l_r[r] = 0.f; }
    for (int d = 0; d < 5; d++) acco[d] = (floatx4){0.f, 0.f, 0.f, 0.f};

    for (int kc = 0; kc < SEQ; kc += 64) {
        const u16* Kb = Khi + (size_t)(h * SEQ + kc) * HDP;
        for (int i = t; i < 64 * 12; i += 256) {
            int row = i / 12, blk = i % 12;
            *(uint4*)&kts[row * 104 + blk * 8] = *(const uint4*)&Kb[row * HDP + blk * 8];
        }
        const u16* Vhb = Vthi + (size_t)h * HD * SEQ + kc;
        const u16* Vlb = Vtlo + (size_t)h * HD * SEQ + kc;
        for (int i = t; i < 80 * 8; i += 256) {
            int row = i / 8, blk = i % 8;
            *(uint4*)&vth[row * 72 + blk * 8] = *(const uint4*)&Vhb[(size_t)row * SEQ + blk * 8];
            *(uint4*)&vtl[row * 72 + blk * 8] = *(const uint4*)&Vlb[(size_t)row * SEQ + blk * 8];
        }
        __syncthreads();

        floatx4 sa[4];
        for (int nt = 0; nt < 4; nt++) {
            floatx4 s = (floatx4){0.f, 0.f, 0.f, 0.f};
            int nb = (nt * 16 + (lane & 15)) * 104 + (lane >> 4) * 8;
            short8 b0 = *(const short8*)&kts[nb];
            short8 b1 = *(const short8*)&kts[nb + 32];
            short8 b2 = *(const short8*)&kts[nb + 64];
            s = __builtin_amdgcn_mfma_f32_16x16x32_bf16(aqh[0], b0, s, 0, 0, 0);
            s = __builtin_amdgcn_mfma_f32_16x16x32_bf16(aqh[1], b1, s, 0, 0, 0);
            s = __builtin_amdgcn_mfma_f32_16x16x32_bf16(aqh[2], b2, s, 0, 0, 0);
            s = __builtin_amdgcn_mfma_f32_16x16x32_bf16(aql[0], b0, s, 0, 0, 0);
            s = __builtin_amdgcn_mfma_f32_16x16x32_bf16(aql[1], b1, s, 0, 0, 0);
            s = __builtin_amdgcn_mfma_f32_16x16x32_bf16(aql[2], b2, s, 0, 0, 0);
            sa[nt] = s;
        }
        float mn[4], alpha[4];
        for (int r = 0; r < 4; r++) {
            float mx = fmaxf(fmaxf(sa[0][r], sa[1][r]), fmaxf(sa[2][r], sa[3][r]));
            mx = fmaxf(mx, __shfl_xor(mx, 1));
            mx = fmaxf(mx, __shfl_xor(mx, 2));
            mx = fmaxf(mx, __shfl_xor(mx, 4));
            mx = fmaxf(mx, __shfl_xor(mx, 8));
            mn[r] = fmaxf(m_r[r], mx);
            alpha[r] = __expf(m_r[r] - mn[r]);
            m_r[r] = mn[r];
        }
        for (int r = 0; r < 4; r++) {
            float sum = 0.f;
            for (int nt = 0; nt < 4; nt++) {
                float pv = __expf(sa[nt][r] - mn[r]);
                sa[nt][r] = pv;
                sum += pv;
            }
            sum += __shfl_xor(sum, 1);
            sum += __shfl_xor(sum, 2);
            sum += __shfl_xor(sum, 4);
            sum += __shfl_xor(sum, 8);
            l_r[r] = l_r[r] * alpha[r] + sum;
            for (int d = 0; d < 5; d++) acco[d][r] *= alpha[r];
        }
        for (int nt = 0; nt < 4; nt++)
            for (int r = 0; r < 4; r++)
                pls[(w * 16 + (lane >> 4) * 4 + r) * 72 + nt * 16 + (lane & 15)] = f2bf(sa[nt][r]);
        __syncthreads();
        for (int c = 0; c < 2; c++) {
            short8 ap = *(const short8*)&pls[(w * 16 + (lane & 15)) * 72 + c * 32 + (lane >> 4) * 8];
            for (int d = 0; d < 5; d++) {
                int vb = (d * 16 + (lane & 15)) * 72 + c * 32 + (lane >> 4) * 8;
                short8 bh = *(const short8*)&vth[vb];
                short8 bl = *(const short8*)&vtl[vb];
                acco[d] = __builtin_amdgcn_mfma_f32_16x16x32_bf16(ap, bh, acco[d], 0, 0, 0);
                acco[d] = __builtin_amdgcn_mfma_f32_16x16x32_bf16(ap, bl, acco[d], 0, 0, 0);
            }
        }
        __syncthreads();
    }
    for (int d = 0; d < 5; d++) {
        int col = h * HD + d * 16 + (lane & 15);
        for (int r = 0; r < 4; r++) {
            int row = q0 + w * 16 + (lane >> 4) * 4 + r;
            float o = acco[d][r] / l_r[r];
            u16 hi = f2bf(o);
            atthi[(size_t)row * HID + col] = hi;
            attlo[(size_t)row * HID + col] = f2bf(o - bf2f(hi));
        }
    }
}

extern "C" void kernel_launch(void* const* d_in, const int* in_sizes, int n_in,
                              void* d_out, int out_size, void* d_ws, size_t ws_size,
                              hipStream_t stream) {
    const float* hs   = (const float*)d_in[0];
    const int*   pos  = (const int*)d_in[1];
    const float* qkvw = (const float*)d_in[2];
    const float* qkvb = (const float*)d_in[3];
    const float* ow   = (const float*)d_in[4];
    const float* ob   = (const float*)d_in[5];
    float* out = (float*)d_out;

    char* p = (char*)d_ws;
    auto alloc = [&](size_t bytes) {
        char* r = p;
        p += (bytes + 255) & ~(size_t)255;
        return r;
    };
    float* cosb  = (float*)alloc((size_t)SEQ * 40 * 4);
    float* sinb  = (float*)alloc((size_t)SEQ * 40 * 4);
    u16* owThi   = (u16*)alloc((size_t)HID * HID * 2);
    u16* owTlo   = (u16*)alloc((size_t)HID * HID * 2);
    // pool1: phase A = hidden hi/lo + qkv_w^T hi/lo; phase B = Q hi/lo + K hi (aliased)
    char* pool1  = alloc(35389440);
    u16* hHi  = (u16*)pool1;
    u16* hLo  = (u16*)(pool1 + 7864320);
    u16* wThi = (u16*)(pool1 + 15728640);
    u16* wTlo = (u16*)(pool1 + 25559040);
    u16* Qhi  = (u16*)pool1;                    // phase B
    u16* Qlo  = (u16*)(pool1 + 9437184);
    u16* Khi  = (u16*)(pool1 + 18874368);
    // pool2: phase A = qkv f32 scratch; phase B = attn_out hi/lo (aliased)
    char* pool2 = alloc((size_t)SEQ * NQKV * 4);
    float* qkv_s = (float*)pool2;
    u16* atthi = (u16*)pool2;
    u16* attlo = (u16*)(pool2 + 7864320);
    u16* Vthi = (u16*)alloc((size_t)NH * HD * SEQ * 2);
    u16* Vtlo = (u16*)alloc((size_t)NH * HD * SEQ * 2);

    hipLaunchKernelGGL(rope_tables_k, dim3(SEQ), dim3(64), 0, stream, pos, cosb, sinb);
    hipLaunchKernelGGL(split_bf16_k, dim3((SEQ * HID + 255) / 256), dim3(256), 0, stream,
                       hs, hHi, hLo, SEQ * HID);
    hipLaunchKernelGGL(transpose_split_k, dim3(NQKV / 32, HID / 32), dim3(256), 0, stream,
                       qkvw, wThi, wTlo, HID, NQKV);
    hipLaunchKernelGGL(transpose_split_k, dim3(HID / 32, HID / 32), dim3(256), 0, stream,
                       ow, owThi, owTlo, HID, HID);
    hipLaunchKernelGGL(gemm_split_k, dim3(NQKV / 128, SEQ / 128), dim3(256), 0, stream,
                       hHi, hLo, wThi, wTlo, qkvb, qkv_s, SEQ, NQKV, HID);
    hipLaunchKernelGGL(pack_qkv_k, dim3(SEQ / 64, NH), dim3(256), 0, stream,
                       qkv_s, cosb, sinb, Qhi, Qlo, Khi, Vthi, Vtlo);
    hipLaunchKernelGGL(attn_k, dim3(SEQ / 64, NH), dim3(256), 0, stream,
                       Qhi, Qlo, Khi, Vthi, Vtlo, atthi, attlo);
    hipLaunchKernelGGL(gemm_split_k, dim3(HID / 128, SEQ / 128), dim3(256), 0, stream,
                       atthi, attlo, owThi, owTlo, ob, out, SEQ, HID, HID);
}

// Round 2
// 415.520 us; speedup vs baseline: 1.5037x; 1.5037x over previous
//
#include <hip/hip_runtime.h>

#define SEQ  3072
#define HID  1280
#define NH   16
#define HD   80
#define HDP  96
#define NQKV 3840

typedef unsigned short u16;
typedef __attribute__((ext_vector_type(8))) short short8;
typedef __attribute__((ext_vector_type(4))) float floatx4;

__device__ __forceinline__ u16 f2bf(float x) {
    unsigned int u = __float_as_uint(x);
    u += 0x7fffu + ((u >> 16) & 1u);
    return (u16)(u >> 16);
}
__device__ __forceinline__ float bf2f(u16 b) {
    return __uint_as_float(((unsigned int)b) << 16);
}

typedef const __attribute__((address_space(1))) unsigned int* gp1_t;
typedef __attribute__((address_space(3))) unsigned int* lp3_t;
__device__ __forceinline__ void gld16(const void* g, void* l) {
    __builtin_amdgcn_global_load_lds((gp1_t)g, (lp3_t)l, 16, 0, 0);
}

// ---------------- rope tables: cos/sin [SEQ][40] ----------------
__global__ void rope_tables_k(const int* __restrict__ pos, float* __restrict__ cosb,
                              float* __restrict__ sinb) {
    int s = blockIdx.x;
    int j = threadIdx.x;
    if (j >= 40) return;
    float p = (float)((j < 20) ? pos[s * 2] : pos[s * 2 + 1]);
    int i = (j < 20) ? j : j - 20;
    float inv = powf(10000.0f, -(float)i / 20.0f);
    float a = p * inv;
    cosb[s * 40 + j] = cosf(a);
    sinb[s * 40 + j] = sinf(a);
}

// ---------------- split f32 -> bf16 hi/lo ----------------
__global__ void split_bf16_k(const float* __restrict__ x, u16* __restrict__ hi,
                             u16* __restrict__ lo, int n) {
    int i = blockIdx.x * 256 + threadIdx.x;
    if (i >= n) return;
    float v = x[i];
    u16 h = f2bf(v);
    hi[i] = h;
    lo[i] = f2bf(v - bf2f(h));
}

// ---------------- transpose + split: w[K][N] -> t[N][K] hi/lo ----------------
__global__ void transpose_split_k(const float* __restrict__ w, u16* __restrict__ thi,
                                  u16* __restrict__ tlo, int K, int N) {
    __shared__ float tile[32][33];
    int n0 = blockIdx.x * 32, k0 = blockIdx.y * 32;
    int c = threadIdx.x & 31, r8 = threadIdx.x >> 5;
    for (int rr = r8; rr < 32; rr += 8)
        tile[rr][c] = w[(size_t)(k0 + rr) * N + n0 + c];
    __syncthreads();
    for (int rr = r8; rr < 32; rr += 8) {
        float x = tile[c][rr];
        u16 h = f2bf(x);
        size_t o = (size_t)(n0 + rr) * K + k0 + c;
        thi[o] = h;
        tlo[o] = f2bf(x - bf2f(h));
    }
}

// ---------------- split GEMM with global_load_lds staging ----------------
// C[M][N] = A[M][K] * Bt[N][K]^T + bias; 3-product bf16 split.
// LDS: pitch 32 elems (64B rows), 16B chunks XOR-swizzled by ((row>>1)&3) so
// frag reads (stride 64B) spread across all 32 banks.
__global__ __launch_bounds__(256, 2) void gemm_split_k(
    const u16* __restrict__ Ahi, const u16* __restrict__ Alo,
    const u16* __restrict__ Bhi, const u16* __restrict__ Blo,
    const float* __restrict__ bias, float* __restrict__ C,
    int M, int N, int K) {
    __shared__ u16 lAh[128 * 32], lAl[128 * 32], lBh[128 * 32], lBl[128 * 32];
    const int t = threadIdx.x, lane = t & 63, w = t >> 6;
    const int m0 = blockIdx.y * 128, n0 = blockIdx.x * 128;
    const int wm = (w >> 1) * 64, wn = (w & 1) * 64;

    floatx4 acc[4][4];
    for (int mi = 0; mi < 4; mi++)
        for (int ni = 0; ni < 4; ni++) acc[mi][ni] = (floatx4){0.f, 0.f, 0.f, 0.f};

    // staging geometry: wave w stages rows w*32 .. w*32+31 (2 chunks of 16 rows)
    const int r0 = w * 32 + (lane >> 2);
    const int r1 = r0 + 16;
    const int bl0 = (((lane & 3) ^ ((r0 >> 1) & 3)) << 3);  // logical elem offset
    const int bl1 = (((lane & 3) ^ ((r1 >> 1) & 3)) << 3);
    const size_t gA0 = (size_t)(m0 + r0) * K + bl0;
    const size_t gA1 = (size_t)(m0 + r1) * K + bl1;
    const size_t gB0 = (size_t)(n0 + r0) * K + bl0;
    const size_t gB1 = (size_t)(n0 + r1) * K + bl1;
    u16* dA0 = &lAh[(w * 32) * 32];
    u16* dA1 = &lAh[(w * 32 + 16) * 32];
    u16* dAl0 = &lAl[(w * 32) * 32];
    u16* dAl1 = &lAl[(w * 32 + 16) * 32];
    u16* dB0 = &lBh[(w * 32) * 32];
    u16* dB1 = &lBh[(w * 32 + 16) * 32];
    u16* dBl0 = &lBl[(w * 32) * 32];
    u16* dBl1 = &lBl[(w * 32 + 16) * 32];

    for (int k0 = 0; k0 < K; k0 += 32) {
        gld16(Ahi + gA0 + k0, dA0);
        gld16(Ahi + gA1 + k0, dA1);
        gld16(Alo + gA0 + k0, dAl0);
        gld16(Alo + gA1 + k0, dAl1);
        gld16(Bhi + gB0 + k0, dB0);
        gld16(Bhi + gB1 + k0, dB1);
        gld16(Blo + gB0 + k0, dBl0);
        gld16(Blo + gB1 + k0, dBl1);
        __syncthreads();
        short8 ah[4], al[4], bh[4], bl[4];
        for (int mi = 0; mi < 4; mi++) {
            int row = wm + mi * 16 + (lane & 15);
            int off = row * 32 + ((((lane >> 4) ^ ((row >> 1) & 3))) << 3);
            ah[mi] = *(const short8*)&lAh[off];
            al[mi] = *(const short8*)&lAl[off];
        }
        for (int ni = 0; ni < 4; ni++) {
            int row = wn + ni * 16 + (lane & 15);
            int off = row * 32 + ((((lane >> 4) ^ ((row >> 1) & 3))) << 3);
            bh[ni] = *(const short8*)&lBh[off];
            bl[ni] = *(const short8*)&lBl[off];
        }
        for (int mi = 0; mi < 4; mi++)
            for (int ni = 0; ni < 4; ni++) {
                acc[mi][ni] = __builtin_amdgcn_mfma_f32_16x16x32_bf16(ah[mi], bh[ni], acc[mi][ni], 0, 0, 0);
                acc[mi][ni] = __builtin_amdgcn_mfma_f32_16x16x32_bf16(ah[mi], bl[ni], acc[mi][ni], 0, 0, 0);
                acc[mi][ni] = __builtin_amdgcn_mfma_f32_16x16x32_bf16(al[mi], bh[ni], acc[mi][ni], 0, 0, 0);
            }
        __syncthreads();
    }
    for (int mi = 0; mi < 4; mi++)
        for (int ni = 0; ni < 4; ni++) {
            int col = n0 + wn + ni * 16 + (lane & 15);
            int rowb = m0 + wm + mi * 16 + (lane >> 4) * 4;
            float b = bias[col];
            for (int r = 0; r < 4; r++)
                C[(size_t)(rowb + r) * N + col] = acc[mi][ni][r] + b;
        }
}

// ---------------- pack: rope+scale Q,K -> bf16 [h][s][96]; V -> Vt[h][80][SEQ] ----------------
__global__ void pack_qkv_k(const float* __restrict__ qkv, const float* __restrict__ cosb,
                           const float* __restrict__ sinb,
                           u16* __restrict__ Qh, u16* __restrict__ Kh, u16* __restrict__ Vt) {
    __shared__ float lv[80 * 65];
    const int t = threadIdx.x;
    const int h = blockIdx.y, s0 = blockIdx.x * 64;
    const float scale = 0.11180339887498949f;  // 80^-0.5

    for (int i = t; i < 64 * 40; i += 256) {
        int rl = i / 40, j = i % 40;
        int s = s0 + rl;
        float c = cosb[s * 40 + j], sn = sinb[s * 40 + j];
        const float* qb = qkv + (size_t)s * NQKV + h * HD;
        float q1 = qb[j], q2 = qb[j + 40];
        size_t qo = (size_t)(h * SEQ + s) * HDP;
        Qh[qo + j] = f2bf((q1 * c - q2 * sn) * scale);
        Qh[qo + j + 40] = f2bf((q2 * c + q1 * sn) * scale);
        const float* kb = qb + HID;
        float k1 = kb[j], k2 = kb[j + 40];
        Kh[qo + j] = f2bf(k1 * c - k2 * sn);
        Kh[qo + j + 40] = f2bf(k2 * c + k1 * sn);
    }
    for (int i = t; i < 64 * 16; i += 256) {  // zero-pad dims 80..95
        int rl = i / 16, pc = i % 16;
        size_t qo = (size_t)(h * SEQ + s0 + rl) * HDP + 80 + pc;
        Qh[qo] = 0;
        Kh[qo] = 0;
    }
    for (int i = t; i < 64 * 80; i += 256) {
        int rl = i / 80, d = i % 80;
        lv[d * 65 + rl] = qkv[(size_t)(s0 + rl) * NQKV + 2 * HID + h * HD + d];
    }
    __syncthreads();
    for (int i = t; i < 80 * 64; i += 256) {
        int d = i / 64, c2 = i % 64;
        Vt[((size_t)h * HD + d) * SEQ + s0 + c2] = f2bf(lv[d * 65 + c2]);
    }
}

// ---------------- flash attention, S^T orientation ----------------
// S^T = mfma(A=K, B=Q): lane owns query q=lane&15; softmax stats in-lane + 2 shfl.
// P^T roundtrip through wave-private swizzled LDS (no barrier).
// O^T = mfma(A=Vt, B=P^T): alpha/l rescale per-lane.
__global__ __launch_bounds__(256, 3) void attn_k(
    const u16* __restrict__ Qh, const u16* __restrict__ Kh, const u16* __restrict__ Vt,
    u16* __restrict__ atthi, u16* __restrict__ attlo) {
    __shared__ u16 qts[64 * 104];
    __shared__ u16 kts[64 * 104];
    __shared__ u16 vts[80 * 72];
    __shared__ u16 pls[4][1024];  // per-wave 16q x 64k, row 128B, 16B units XOR (q&7)

    const int t = threadIdx.x, lane = t & 63, w = t >> 6;
    const int quad = lane >> 4, qi = lane & 15;
    const int h = blockIdx.y, q0 = blockIdx.x * 64;

    const u16* Qb = Qh + (size_t)(h * SEQ + q0) * HDP;
    for (int i = t; i < 64 * 12; i += 256) {
        int row = i / 12, blk = i % 12;
        *(uint4*)&qts[row * 104 + blk * 8] = *(const uint4*)&Qb[row * HDP + blk * 8];
    }
    __syncthreads();
    short8 bq[3];
    for (int ks = 0; ks < 3; ks++)
        bq[ks] = *(const short8*)&qts[(w * 16 + qi) * 104 + ks * 32 + quad * 8];

    float m_i = -1e30f, l_i = 0.f;
    floatx4 acco[5];
    for (int dt = 0; dt < 5; dt++) acco[dt] = (floatx4){0.f, 0.f, 0.f, 0.f};

    char* const myp = (char*)&pls[w][0];

    for (int kc = 0; kc < SEQ; kc += 64) {
        const u16* Kb = Kh + (size_t)(h * SEQ + kc) * HDP;
        for (int i = t; i < 64 * 12; i += 256) {
            int row = i / 12, blk = i % 12;
            *(uint4*)&kts[row * 104 + blk * 8] = *(const uint4*)&Kb[row * HDP + blk * 8];
        }
        const u16* Vb = Vt + (size_t)h * HD * SEQ + kc;
        for (int i = t; i < 80 * 8; i += 256) {
            int row = i / 8, blk = i % 8;
            *(uint4*)&vts[row * 72 + blk * 8] = *(const uint4*)&Vb[(size_t)row * SEQ + blk * 8];
        }
        __syncthreads();

        // S^T[key=kt*16+quad*4+r][q=qi]
        floatx4 sa[4];
        for (int kt = 0; kt < 4; kt++) {
            floatx4 s = (floatx4){0.f, 0.f, 0.f, 0.f};
            for (int ks = 0; ks < 3; ks++) {
                short8 ak = *(const short8*)&kts[(kt * 16 + qi) * 104 + ks * 32 + quad * 8];
                s = __builtin_amdgcn_mfma_f32_16x16x32_bf16(ak, bq[ks], s, 0, 0, 0);
            }
            sa[kt] = s;
        }
        // online softmax: per-lane over 16 values + cross-quad shfl
        float mx = -1e30f;
        for (int kt = 0; kt < 4; kt++)
            for (int r = 0; r < 4; r++) mx = fmaxf(mx, sa[kt][r]);
        mx = fmaxf(mx, __shfl_xor(mx, 16));
        mx = fmaxf(mx, __shfl_xor(mx, 32));
        float mn = fmaxf(m_i, mx);
        float alpha = __expf(m_i - mn);
        m_i = mn;
        float sum = 0.f;
        for (int kt = 0; kt < 4; kt++)
            for (int r = 0; r < 4; r++) {
                float pv = __expf(sa[kt][r] - mn);
                sa[kt][r] = pv;
                sum += pv;
            }
        sum += __shfl_xor(sum, 16);
        sum += __shfl_xor(sum, 32);
        l_i = l_i * alpha + sum;
        for (int dt = 0; dt < 5; dt++)
            for (int r = 0; r < 4; r++) acco[dt][r] *= alpha;

        // write P^T rows (q=qi): keys kt*16+quad*4..+3 packed bf16x4, swizzled
        for (int kt = 0; kt < 4; kt++) {
            uint2 pk;
            pk.x = (unsigned int)f2bf(sa[kt][0]) | ((unsigned int)f2bf(sa[kt][1]) << 16);
            pk.y = (unsigned int)f2bf(sa[kt][2]) | ((unsigned int)f2bf(sa[kt][3]) << 16);
            int u = 2 * kt + (quad >> 1);
            *(uint2*)(myp + qi * 128 + ((u ^ (qi & 7)) << 4) + ((quad & 1) << 3)) = pk;
        }
        // PV: O^T += Vt_frag * P^T_frag  (wave-private LDS, no barrier)
        for (int c2 = 0; c2 < 2; c2++) {
            int u = 4 * c2 + quad;
            short8 bp = *(const short8*)(myp + qi * 128 + ((u ^ (qi & 7)) << 4));
            for (int dt = 0; dt < 5; dt++) {
                short8 av = *(const short8*)&vts[(dt * 16 + qi) * 72 + c2 * 32 + quad * 8];
                acco[dt] = __builtin_amdgcn_mfma_f32_16x16x32_bf16(av, bp, acco[dt], 0, 0, 0);
            }
        }
        __syncthreads();
    }
    float linv = 1.0f / l_i;
    for (int dt = 0; dt < 5; dt++)
        for (int r = 0; r < 4; r++) {
            float o = acco[dt][r] * linv;
            int d = dt * 16 + quad * 4 + r;
            size_t idx = (size_t)(q0 + w * 16 + qi) * HID + h * HD + d;
            u16 hi = f2bf(o);
            atthi[idx] = hi;
            attlo[idx] = f2bf(o - bf2f(hi));
        }
}

extern "C" void kernel_launch(void* const* d_in, const int* in_sizes, int n_in,
                              void* d_out, int out_size, void* d_ws, size_t ws_size,
                              hipStream_t stream) {
    const float* hs   = (const float*)d_in[0];
    const int*   pos  = (const int*)d_in[1];
    const float* qkvw = (const float*)d_in[2];
    const float* qkvb = (const float*)d_in[3];
    const float* ow   = (const float*)d_in[4];
    const float* ob   = (const float*)d_in[5];
    float* out = (float*)d_out;

    char* p = (char*)d_ws;
    auto alloc = [&](size_t bytes) {
        char* r = p;
        p += (bytes + 255) & ~(size_t)255;
        return r;
    };
    float* cosb = (float*)alloc((size_t)SEQ * 40 * 4);
    float* sinb = (float*)alloc((size_t)SEQ * 40 * 4);
    u16* owThi = (u16*)alloc((size_t)HID * HID * 2);
    u16* owTlo = (u16*)alloc((size_t)HID * HID * 2);
    // pool1: phase A = hidden hi/lo + qkv_w^T hi/lo; phase B = Qh + Kh (aliased)
    char* pool1 = alloc(35389440);
    u16* hHi  = (u16*)pool1;
    u16* hLo  = (u16*)(pool1 + 7864320);
    u16* wThi = (u16*)(pool1 + 15728640);
    u16* wTlo = (u16*)(pool1 + 25559040);
    u16* Qh   = (u16*)pool1;                  // phase B
    u16* Kh   = (u16*)(pool1 + 9437184);
    // pool2: phase A = qkv f32; phase B = attn out hi/lo (aliased)
    char* pool2 = alloc((size_t)SEQ * NQKV * 4);
    float* qkv_s = (float*)pool2;
    u16* atthi = (u16*)pool2;
    u16* attlo = (u16*)(pool2 + 7864320);
    u16* Vth = (u16*)alloc((size_t)NH * HD * SEQ * 2);

    hipLaunchKernelGGL(rope_tables_k, dim3(SEQ), dim3(64), 0, stream, pos, cosb, sinb);
    hipLaunchKernelGGL(split_bf16_k, dim3((SEQ * HID + 255) / 256), dim3(256), 0, stream,
                       hs, hHi, hLo, SEQ * HID);
    hipLaunchKernelGGL(transpose_split_k, dim3(NQKV / 32, HID / 32), dim3(256), 0, stream,
                       qkvw, wThi, wTlo, HID, NQKV);
    hipLaunchKernelGGL(transpose_split_k, dim3(HID / 32, HID / 32), dim3(256), 0, stream,
                       ow, owThi, owTlo, HID, HID);
    hipLaunchKernelGGL(gemm_split_k, dim3(NQKV / 128, SEQ / 128), dim3(256), 0, stream,
                       hHi, hLo, wThi, wTlo, qkvb, qkv_s, SEQ, NQKV, HID);
    hipLaunchKernelGGL(pack_qkv_k, dim3(SEQ / 64, NH), dim3(256), 0, stream,
                       qkv_s, cosb, sinb, Qh, Kh, Vth);
    hipLaunchKernelGGL(attn_k, dim3(SEQ / 64, NH), dim3(256), 0, stream,
                       Qh, Kh, Vth, atthi, attlo);
    hipLaunchKernelGGL(gemm_split_k, dim3(HID / 128, SEQ / 128), dim3(256), 0, stream,
                       atthi, attlo, owThi, owTlo, ob, out, SEQ, HID, HID);
}

// Round 3
// 345.996 us; speedup vs baseline: 1.8058x; 1.2009x over previous
//
#include <hip/hip_runtime.h>

#define SEQ  3072
#define HID  1280
#define NH   16
#define HD   80
#define NQKV 3840

typedef unsigned short u16;
typedef unsigned int u32;
typedef __attribute__((ext_vector_type(8))) short short8;
typedef __attribute__((ext_vector_type(4))) float floatx4;

__device__ __forceinline__ u16 f2bf(float x) {
    u32 u = __float_as_uint(x);
    u += 0x7fffu + ((u >> 16) & 1u);
    return (u16)(u >> 16);
}
__device__ __forceinline__ float bf2f(u16 b) {
    return __uint_as_float(((u32)b) << 16);
}
// round-half-up pack of two f32 -> bf16x2 (cheap; inputs are positive exp values)
__device__ __forceinline__ u32 pack2bf(float a, float b) {
    u32 ua = __float_as_uint(a) + 0x8000u;
    u32 ub = __float_as_uint(b) + 0x8000u;
    return (ua >> 16) | (ub & 0xffff0000u);
}

typedef const __attribute__((address_space(1))) unsigned int* gp1_t;
typedef __attribute__((address_space(3))) unsigned int* lp3_t;
__device__ __forceinline__ void gld16(const void* g, void* l) {
    __builtin_amdgcn_global_load_lds((gp1_t)g, (lp3_t)l, 16, 0, 0);
}

// swizzled 16B-chunk position for Q/K rows (96 elems = 12 chunks): uniform banks
__device__ __forceinline__ int swz_qk(int c, int r) {
    return (c < 8) ? (c ^ (r & 7)) : (8 + ((c - 8) ^ (r & 3)));
}

// ---------------- rope tables: cos/sin [SEQ][40] ----------------
__global__ void rope_tables_k(const int* __restrict__ pos, float* __restrict__ cosb,
                              float* __restrict__ sinb) {
    int s = blockIdx.x;
    int j = threadIdx.x;
    if (j >= 40) return;
    float p = (float)((j < 20) ? pos[s * 2] : pos[s * 2 + 1]);
    int i = (j < 20) ? j : j - 20;
    float inv = powf(10000.0f, -(float)i / 20.0f);
    float a = p * inv;
    cosb[s * 40 + j] = cosf(a);
    sinb[s * 40 + j] = sinf(a);
}

// ---------------- split f32 -> bf16 hi/lo ----------------
__global__ void split_bf16_k(const float* __restrict__ x, u16* __restrict__ hi,
                             u16* __restrict__ lo, int n) {
    int i = blockIdx.x * 256 + threadIdx.x;
    if (i >= n) return;
    float v = x[i];
    u16 h = f2bf(v);
    hi[i] = h;
    lo[i] = f2bf(v - bf2f(h));
}

// ---------------- transpose + split: w[K][N] -> t[N][K] hi/lo ----------------
__global__ void transpose_split_k(const float* __restrict__ w, u16* __restrict__ thi,
                                  u16* __restrict__ tlo, int K, int N) {
    __shared__ float tile[32][33];
    int n0 = blockIdx.x * 32, k0 = blockIdx.y * 32;
    int c = threadIdx.x & 31, r8 = threadIdx.x >> 5;
    for (int rr = r8; rr < 32; rr += 8)
        tile[rr][c] = w[(size_t)(k0 + rr) * N + n0 + c];
    __syncthreads();
    for (int rr = r8; rr < 32; rr += 8) {
        float x = tile[c][rr];
        u16 h = f2bf(x);
        size_t o = (size_t)(n0 + rr) * K + k0 + c;
        thi[o] = h;
        tlo[o] = f2bf(x - bf2f(h));
    }
}

// ---------------- 3-product split GEMM (QKV) ----------------
__global__ __launch_bounds__(256, 2) void gemm_split_k(
    const u16* __restrict__ Ahi, const u16* __restrict__ Alo,
    const u16* __restrict__ Bhi, const u16* __restrict__ Blo,
    const float* __restrict__ bias, float* __restrict__ C,
    int M, int N, int K) {
    __shared__ u16 lAh[128 * 32], lAl[128 * 32], lBh[128 * 32], lBl[128 * 32];
    const int t = threadIdx.x, lane = t & 63, w = t >> 6;
    const int m0 = blockIdx.y * 128, n0 = blockIdx.x * 128;
    const int wm = (w >> 1) * 64, wn = (w & 1) * 64;

    floatx4 acc[4][4];
    for (int mi = 0; mi < 4; mi++)
        for (int ni = 0; ni < 4; ni++) acc[mi][ni] = (floatx4){0.f, 0.f, 0.f, 0.f};

    const int r0 = w * 32 + (lane >> 2);
    const int r1 = r0 + 16;
    const int bl0 = (((lane & 3) ^ ((r0 >> 1) & 3)) << 3);
    const int bl1 = (((lane & 3) ^ ((r1 >> 1) & 3)) << 3);
    const size_t gA0 = (size_t)(m0 + r0) * K + bl0;
    const size_t gA1 = (size_t)(m0 + r1) * K + bl1;
    const size_t gB0 = (size_t)(n0 + r0) * K + bl0;
    const size_t gB1 = (size_t)(n0 + r1) * K + bl1;
    u16* dA0 = &lAh[(w * 32) * 32];
    u16* dA1 = &lAh[(w * 32 + 16) * 32];
    u16* dAl0 = &lAl[(w * 32) * 32];
    u16* dAl1 = &lAl[(w * 32 + 16) * 32];
    u16* dB0 = &lBh[(w * 32) * 32];
    u16* dB1 = &lBh[(w * 32 + 16) * 32];
    u16* dBl0 = &lBl[(w * 32) * 32];
    u16* dBl1 = &lBl[(w * 32 + 16) * 32];

    for (int k0 = 0; k0 < K; k0 += 32) {
        gld16(Ahi + gA0 + k0, dA0);
        gld16(Ahi + gA1 + k0, dA1);
        gld16(Alo + gA0 + k0, dAl0);
        gld16(Alo + gA1 + k0, dAl1);
        gld16(Bhi + gB0 + k0, dB0);
        gld16(Bhi + gB1 + k0, dB1);
        gld16(Blo + gB0 + k0, dBl0);
        gld16(Blo + gB1 + k0, dBl1);
        __syncthreads();
        short8 ah[4], al[4], bh[4], bl[4];
        for (int mi = 0; mi < 4; mi++) {
            int row = wm + mi * 16 + (lane & 15);
            int off = row * 32 + ((((lane >> 4) ^ ((row >> 1) & 3))) << 3);
            ah[mi] = *(const short8*)&lAh[off];
            al[mi] = *(const short8*)&lAl[off];
        }
        for (int ni = 0; ni < 4; ni++) {
            int row = wn + ni * 16 + (lane & 15);
            int off = row * 32 + ((((lane >> 4) ^ ((row >> 1) & 3))) << 3);
            bh[ni] = *(const short8*)&lBh[off];
            bl[ni] = *(const short8*)&lBl[off];
        }
        for (int mi = 0; mi < 4; mi++)
            for (int ni = 0; ni < 4; ni++) {
                acc[mi][ni] = __builtin_amdgcn_mfma_f32_16x16x32_bf16(ah[mi], bh[ni], acc[mi][ni], 0, 0, 0);
                acc[mi][ni] = __builtin_amdgcn_mfma_f32_16x16x32_bf16(ah[mi], bl[ni], acc[mi][ni], 0, 0, 0);
                acc[mi][ni] = __builtin_amdgcn_mfma_f32_16x16x32_bf16(al[mi], bh[ni], acc[mi][ni], 0, 0, 0);
            }
        __syncthreads();
    }
    for (int mi = 0; mi < 4; mi++)
        for (int ni = 0; ni < 4; ni++) {
            int col = n0 + wn + ni * 16 + (lane & 15);
            int rowb = m0 + wm + mi * 16 + (lane >> 4) * 4;
            float b = bias[col];
            for (int r = 0; r < 4; r++)
                C[(size_t)(rowb + r) * N + col] = acc[mi][ni][r] + b;
        }
}

// ---------------- 2-product GEMM (O-proj): A bf16, B hi/lo ----------------
__global__ __launch_bounds__(256, 2) void gemm2_k(
    const u16* __restrict__ A, const u16* __restrict__ Bhi, const u16* __restrict__ Blo,
    const float* __restrict__ bias, float* __restrict__ C, int M, int N, int K) {
    __shared__ u16 lA[128 * 32], lBh[128 * 32], lBl[128 * 32];
    const int t = threadIdx.x, lane = t & 63, w = t >> 6;
    const int m0 = blockIdx.y * 128, n0 = blockIdx.x * 128;
    const int wm = (w >> 1) * 64, wn = (w & 1) * 64;

    floatx4 acc[4][4];
    for (int mi = 0; mi < 4; mi++)
        for (int ni = 0; ni < 4; ni++) acc[mi][ni] = (floatx4){0.f, 0.f, 0.f, 0.f};

    const int r0 = w * 32 + (lane >> 2);
    const int r1 = r0 + 16;
    const int bl0 = (((lane & 3) ^ ((r0 >> 1) & 3)) << 3);
    const int bl1 = (((lane & 3) ^ ((r1 >> 1) & 3)) << 3);
    const size_t gA0 = (size_t)(m0 + r0) * K + bl0;
    const size_t gA1 = (size_t)(m0 + r1) * K + bl1;
    const size_t gB0 = (size_t)(n0 + r0) * K + bl0;
    const size_t gB1 = (size_t)(n0 + r1) * K + bl1;

    for (int k0 = 0; k0 < K; k0 += 32) {
        gld16(A + gA0 + k0, &lA[(w * 32) * 32]);
        gld16(A + gA1 + k0, &lA[(w * 32 + 16) * 32]);
        gld16(Bhi + gB0 + k0, &lBh[(w * 32) * 32]);
        gld16(Bhi + gB1 + k0, &lBh[(w * 32 + 16) * 32]);
        gld16(Blo + gB0 + k0, &lBl[(w * 32) * 32]);
        gld16(Blo + gB1 + k0, &lBl[(w * 32 + 16) * 32]);
        __syncthreads();
        short8 ah[4], bh[4], bl[4];
        for (int mi = 0; mi < 4; mi++) {
            int row = wm + mi * 16 + (lane & 15);
            int off = row * 32 + ((((lane >> 4) ^ ((row >> 1) & 3))) << 3);
            ah[mi] = *(const short8*)&lA[off];
        }
        for (int ni = 0; ni < 4; ni++) {
            int row = wn + ni * 16 + (lane & 15);
            int off = row * 32 + ((((lane >> 4) ^ ((row >> 1) & 3))) << 3);
            bh[ni] = *(const short8*)&lBh[off];
            bl[ni] = *(const short8*)&lBl[off];
        }
        for (int mi = 0; mi < 4; mi++)
            for (int ni = 0; ni < 4; ni++) {
                acc[mi][ni] = __builtin_amdgcn_mfma_f32_16x16x32_bf16(ah[mi], bh[ni], acc[mi][ni], 0, 0, 0);
                acc[mi][ni] = __builtin_amdgcn_mfma_f32_16x16x32_bf16(ah[mi], bl[ni], acc[mi][ni], 0, 0, 0);
            }
        __syncthreads();
    }
    for (int mi = 0; mi < 4; mi++)
        for (int ni = 0; ni < 4; ni++) {
            int col = n0 + wn + ni * 16 + (lane & 15);
            int rowb = m0 + wm + mi * 16 + (lane >> 4) * 4;
            float b = bias[col];
            for (int r = 0; r < 4; r++)
                C[(size_t)(rowb + r) * N + col] = acc[mi][ni][r] + b;
        }
}

// ---------------- pack: rope+scale Q,K -> swizzled [h][s][96]; V -> swizzled Vt[h][80][SEQ] ----------------
__global__ void pack_qkv_k(const float* __restrict__ qkv, const float* __restrict__ cosb,
                           const float* __restrict__ sinb,
                           u16* __restrict__ Qs, u16* __restrict__ Ks, u16* __restrict__ Vs) {
    __shared__ float lv[80 * 65];
    const int t = threadIdx.x;
    const int h = blockIdx.y, s0 = blockIdx.x * 64;
    const float scale = 0.11180339887498949f;  // 80^-0.5

    for (int i = t; i < 64 * 40; i += 256) {
        int rl = i / 40, j = i % 40;
        int s = s0 + rl;
        float c = cosb[s * 40 + j], sn = sinb[s * 40 + j];
        const float* qb = qkv + (size_t)s * NQKV + h * HD;
        float q1 = qb[j], q2 = qb[j + 40];
        size_t base = (size_t)(h * SEQ + s) * 96;
        int j2 = j + 40;
        size_t o1 = base + swz_qk(j >> 3, s) * 8 + (j & 7);
        size_t o2 = base + swz_qk(j2 >> 3, s) * 8 + (j2 & 7);
        Qs[o1] = f2bf((q1 * c - q2 * sn) * scale);
        Qs[o2] = f2bf((q2 * c + q1 * sn) * scale);
        const float* kb = qb + HID;
        float k1 = kb[j], k2 = kb[j + 40];
        Ks[o1] = f2bf(k1 * c - k2 * sn);
        Ks[o2] = f2bf(k2 * c + k1 * sn);
    }
    for (int i = t; i < 64 * 16; i += 256) {  // zero-pad logical elems 80..95
        int rl = i / 16, jj = 80 + i % 16;
        int s = s0 + rl;
        size_t o = (size_t)(h * SEQ + s) * 96 + swz_qk(jj >> 3, s) * 8 + (jj & 7);
        Qs[o] = 0;
        Ks[o] = 0;
    }
    for (int i = t; i < 64 * 80; i += 256) {
        int rl = i / 80, d = i % 80;
        lv[d * 65 + rl] = qkv[(size_t)(s0 + rl) * NQKV + 2 * HID + h * HD + d];
    }
    __syncthreads();
    for (int i = t; i < 80 * 64; i += 256) {
        int d = i / 64, c2l = i % 64;
        int pc = ((c2l >> 3) ^ (d & 7));
        Vs[((size_t)h * HD + d) * SEQ + s0 + pc * 8 + (c2l & 7)] = f2bf(lv[d * 65 + c2l]);
    }
}

// ---------------- flash attention: QT=128, key-split 2, no-max softmax ----------------
__global__ __launch_bounds__(256, 3) void attn_k(
    const u16* __restrict__ Qs, const u16* __restrict__ Ks, const u16* __restrict__ Vs,
    float* __restrict__ Op, float* __restrict__ lp) {
    __shared__ u16 kbuf[2][6144];  // 12KB each; [0..1] doubles as 24KB Q staging
    __shared__ u16 vbuf[2][5120];  // 10KB each
    __shared__ u16 pls[4][1024];   // 2KB per wave (wave-private P transpose)

    const int t = threadIdx.x, lane = t & 63, w = t >> 6;
    const int qi = lane & 15, quad = lane >> 4;
    const int h = blockIdx.y, q0 = blockIdx.x * 128, ksp = blockIdx.z;
    const int kc0 = ksp * (SEQ / 2);
    u16* const kflat = &kbuf[0][0];

    // ---- stage Q (128 rows x 192B, contiguous) ----
    {
        const u16* Qt = Qs + (size_t)(h * SEQ + q0) * 96;
        for (int j = 0; j < 6; j++) {
            int o = (w * 6 + j) * 512;
            gld16(Qt + o + lane * 8, kflat + o);
        }
    }
    __syncthreads();
    short8 bq[2][3];
    for (int qg = 0; qg < 2; qg++) {
        int row = w * 32 + qg * 16 + qi;
        for (int k3 = 0; k3 < 3; k3++) {
            int p = (k3 < 2) ? ((4 * k3 + quad) ^ (qi & 7)) : (8 + (quad ^ (qi & 3)));
            bq[qg][k3] = *(const short8*)&kflat[(row * 12 + p) * 8];
        }
    }
    __syncthreads();

    float l_lane[2] = {0.f, 0.f};
    floatx4 acco[2][5];
    for (int qg = 0; qg < 2; qg++)
        for (int dt = 0; dt < 5; dt++) acco[qg][dt] = (floatx4){0.f, 0.f, 0.f, 0.f};

    auto stage = [&](int it, int buf) {
        int kc = kc0 + it * 64;
        const u16* Kt = Ks + (size_t)(h * SEQ + kc) * 96;
        for (int j = 0; j < 3; j++) {
            int o = (w * 3 + j) * 512;
            gld16(Kt + o + lane * 8, &kbuf[buf][o]);
        }
        const u16* Vt = Vs + (size_t)h * HD * SEQ + kc;
        for (int i = w; i < 10; i += 4) {
            int p16 = i * 64 + lane;
            int d = p16 >> 3, pc = p16 & 7;
            gld16(Vt + (size_t)d * SEQ + pc * 8, &vbuf[buf][i * 512]);
        }
    };
    stage(0, 0);
    __syncthreads();

    const int NT = (SEQ / 2) / 64;  // 24
    char* const myp = (char*)&pls[w][0];
    for (int it = 0; it < NT; it++) {
        int cur = it & 1;
        if (it + 1 < NT) stage(it + 1, cur ^ 1);
        const u16* kb = &kbuf[cur][0];
        const u16* vb = &vbuf[cur][0];
        for (int c2 = 0; c2 < 2; c2++) {
            for (int ktl = 0; ktl < 2; ktl++) {
                int kt = c2 * 2 + ktl;
                int arow = kt * 16 + qi;
                short8 ak[3];
                for (int k3 = 0; k3 < 3; k3++) {
                    int p = (k3 < 2) ? ((4 * k3 + quad) ^ (qi & 7)) : (8 + (quad ^ (qi & 3)));
                    ak[k3] = *(const short8*)&kb[(arow * 12 + p) * 8];
                }
                for (int qg = 0; qg < 2; qg++) {
                    floatx4 s = (floatx4){0.f, 0.f, 0.f, 0.f};
                    s = __builtin_amdgcn_mfma_f32_16x16x32_bf16(ak[0], bq[qg][0], s, 0, 0, 0);
                    s = __builtin_amdgcn_mfma_f32_16x16x32_bf16(ak[1], bq[qg][1], s, 0, 0, 0);
                    s = __builtin_amdgcn_mfma_f32_16x16x32_bf16(ak[2], bq[qg][2], s, 0, 0, 0);
                    float e0 = __expf(s[0]), e1 = __expf(s[1]);
                    float e2 = __expf(s[2]), e3 = __expf(s[3]);
                    l_lane[qg] += (e0 + e1) + (e2 + e3);
                    uint2 pk;
                    pk.x = pack2bf(e0, e1);
                    pk.y = pack2bf(e2, e3);
                    int u = 2 * ktl + (quad >> 1);
                    *(uint2*)(myp + qg * 1024 + qi * 64 + ((u ^ (qi & 3)) << 4) + ((quad & 1) << 3)) = pk;
                }
            }
            short8 bp0 = *(const short8*)(myp + qi * 64 + ((quad ^ (qi & 3)) << 4));
            short8 bp1 = *(const short8*)(myp + 1024 + qi * 64 + ((quad ^ (qi & 3)) << 4));
            int pv = (4 * c2 + quad) ^ (qi & 7);
            for (int dt = 0; dt < 5; dt++) {
                short8 av = *(const short8*)&vb[((dt * 16 + qi) * 8 + pv) * 8];
                acco[0][dt] = __builtin_amdgcn_mfma_f32_16x16x32_bf16(av, bp0, acco[0][dt], 0, 0, 0);
                acco[1][dt] = __builtin_amdgcn_mfma_f32_16x16x32_bf16(av, bp1, acco[1][dt], 0, 0, 0);
            }
        }
        __syncthreads();
    }

    for (int qg = 0; qg < 2; qg++) {
        float lq = l_lane[qg];
        lq += __shfl_xor(lq, 16);
        lq += __shfl_xor(lq, 32);
        int q = q0 + w * 32 + qg * 16 + qi;
        if (quad == 0) lp[(size_t)(ksp * NH + h) * SEQ + q] = lq;
        for (int dt = 0; dt < 5; dt++)
            for (int r = 0; r < 4; r++) {
                int d = dt * 16 + quad * 4 + r;
                Op[((size_t)(ksp * NH + h) * HD + d) * SEQ + q] = acco[qg][dt][r];
            }
    }
}

// ---------------- merge key-split partials -> att bf16 [SEQ][HID] ----------------
__global__ void merge_k(const float* __restrict__ Op, const float* __restrict__ lp,
                        u16* __restrict__ att) {
    __shared__ float ls[HD * 65];
    __shared__ float li[64];
    const int t = threadIdx.x;
    const int h = blockIdx.y, q0 = blockIdx.x * 64;
    for (int i = t; i < HD * 64; i += 256) {
        int d = i / 64, ql = i % 64;
        size_t a0 = ((size_t)h * HD + d) * SEQ + q0 + ql;
        size_t a1 = ((size_t)(NH + h) * HD + d) * SEQ + q0 + ql;
        ls[d * 65 + ql] = Op[a0] + Op[a1];
    }
    if (t < 64)
        li[t] = 1.0f / (lp[(size_t)h * SEQ + q0 + t] + lp[(size_t)(NH + h) * SEQ + q0 + t]);
    __syncthreads();
    for (int i = t; i < 64 * HD; i += 256) {
        int ql = i / HD, d = i % HD;
        att[(size_t)(q0 + ql) * HID + h * HD + d] = f2bf(ls[d * 65 + ql] * li[ql]);
    }
}

extern "C" void kernel_launch(void* const* d_in, const int* in_sizes, int n_in,
                              void* d_out, int out_size, void* d_ws, size_t ws_size,
                              hipStream_t stream) {
    const float* hs   = (const float*)d_in[0];
    const int*   pos  = (const int*)d_in[1];
    const float* qkvw = (const float*)d_in[2];
    const float* qkvb = (const float*)d_in[3];
    const float* ow   = (const float*)d_in[4];
    const float* ob   = (const float*)d_in[5];
    float* out = (float*)d_out;

    char* p = (char*)d_ws;
    auto alloc = [&](size_t bytes) {
        char* r = p;
        p += (bytes + 255) & ~(size_t)255;
        return r;
    };
    float* cosb = (float*)alloc((size_t)SEQ * 40 * 4);
    float* sinb = (float*)alloc((size_t)SEQ * 40 * 4);
    u16* owThi = (u16*)alloc((size_t)HID * HID * 2);
    u16* owTlo = (u16*)alloc((size_t)HID * HID * 2);
    // pool1: phase A = hidden hi/lo + qkv_w^T hi/lo; phase B = Qs + Ks (aliased)
    char* pool1 = alloc(35389440);
    u16* hHi  = (u16*)pool1;
    u16* hLo  = (u16*)(pool1 + 7864320);
    u16* wThi = (u16*)(pool1 + 15728640);
    u16* wTlo = (u16*)(pool1 + 25559040);
    u16* Qs   = (u16*)pool1;                  // phase B
    u16* Ks   = (u16*)(pool1 + 9437184);
    // pool2: phase A = qkv f32; phase B = att bf16 + Op partials + l partials
    char* pool2 = alloc((size_t)SEQ * NQKV * 4);
    float* qkv_s = (float*)pool2;
    u16* att  = (u16*)pool2;
    float* Op = (float*)(pool2 + 7864320);
    float* lp = (float*)(pool2 + 39321600);
    u16* Vs = (u16*)alloc((size_t)NH * HD * SEQ * 2);

    hipLaunchKernelGGL(rope_tables_k, dim3(SEQ), dim3(64), 0, stream, pos, cosb, sinb);
    hipLaunchKernelGGL(split_bf16_k, dim3((SEQ * HID + 255) / 256), dim3(256), 0, stream,
                       hs, hHi, hLo, SEQ * HID);
    hipLaunchKernelGGL(transpose_split_k, dim3(NQKV / 32, HID / 32), dim3(256), 0, stream,
                       qkvw, wThi, wTlo, HID, NQKV);
    hipLaunchKernelGGL(transpose_split_k, dim3(HID / 32, HID / 32), dim3(256), 0, stream,
                       ow, owThi, owTlo, HID, HID);
    hipLaunchKernelGGL(gemm_split_k, dim3(NQKV / 128, SEQ / 128), dim3(256), 0, stream,
                       hHi, hLo, wThi, wTlo, qkvb, qkv_s, SEQ, NQKV, HID);
    hipLaunchKernelGGL(pack_qkv_k, dim3(SEQ / 64, NH), dim3(256), 0, stream,
                       qkv_s, cosb, sinb, Qs, Ks, Vs);
    hipLaunchKernelGGL(attn_k, dim3(SEQ / 128, NH, 2), dim3(256), 0, stream,
                       Qs, Ks, Vs, Op, lp);
    hipLaunchKernelGGL(merge_k, dim3(SEQ / 64, NH), dim3(256), 0, stream, Op, lp, att);
    hipLaunchKernelGGL(gemm2_k, dim3(HID / 128, SEQ / 128), dim3(256), 0, stream,
                       att, owThi, owTlo, ob, out, SEQ, HID, HID);
}

// Round 4
// 256.857 us; speedup vs baseline: 2.4325x; 1.3470x over previous
//
#include <hip/hip_runtime.h>

#define SEQ  3072
#define HID  1280
#define NH   16
#define HD   80
#define NQKV 3840

typedef unsigned short u16;
typedef unsigned int u32;
typedef __attribute__((ext_vector_type(8))) short short8;
typedef __attribute__((ext_vector_type(4))) float floatx4;

__device__ __forceinline__ u16 f2bf(float x) {
    u32 u = __float_as_uint(x);
    u += 0x7fffu + ((u >> 16) & 1u);
    return (u16)(u >> 16);
}
__device__ __forceinline__ float bf2f(u16 b) {
    return __uint_as_float(((u32)b) << 16);
}
// round-half-up pack of two f32 -> bf16x2 (cheap; inputs are positive exp values)
__device__ __forceinline__ u32 pack2bf(float a, float b) {
    u32 ua = __float_as_uint(a) + 0x8000u;
    u32 ub = __float_as_uint(b) + 0x8000u;
    return (ua >> 16) | (ub & 0xffff0000u);
}

typedef const __attribute__((address_space(1))) unsigned int* gp1_t;
typedef __attribute__((address_space(3))) unsigned int* lp3_t;
__device__ __forceinline__ void gld16(const void* g, void* l) {
    __builtin_amdgcn_global_load_lds((gp1_t)g, (lp3_t)l, 16, 0, 0);
}

// swizzled 16B-chunk position for Q/K rows (96 elems = 12 chunks): uniform banks
__device__ __forceinline__ int swz_qk(int c, int r) {
    return (c < 8) ? (c ^ (r & 7)) : (8 + ((c - 8) ^ (r & 3)));
}

// ---------------- rope tables: cos/sin [SEQ][40] ----------------
__global__ void rope_tables_k(const int* __restrict__ pos, float* __restrict__ cosb,
                              float* __restrict__ sinb) {
    int s = blockIdx.x;
    int j = threadIdx.x;
    if (j >= 40) return;
    float p = (float)((j < 20) ? pos[s * 2] : pos[s * 2 + 1]);
    int i = (j < 20) ? j : j - 20;
    float inv = powf(10000.0f, -(float)i / 20.0f);
    float a = p * inv;
    cosb[s * 40 + j] = cosf(a);
    sinb[s * 40 + j] = sinf(a);
}

// ---------------- cast f32 -> bf16 ----------------
__global__ void cast_bf16_k(const float* __restrict__ x, u16* __restrict__ hi, int n) {
    int i = blockIdx.x * 256 + threadIdx.x;
    if (i >= n) return;
    hi[i] = f2bf(x[i]);
}

// ---------------- transpose + cast: w[K][N] -> t[N][K] bf16 ----------------
__global__ void transpose_cast_k(const float* __restrict__ w, u16* __restrict__ thi,
                                 int K, int N) {
    __shared__ float tile[32][33];
    int n0 = blockIdx.x * 32, k0 = blockIdx.y * 32;
    int c = threadIdx.x & 31, r8 = threadIdx.x >> 5;
    for (int rr = r8; rr < 32; rr += 8)
        tile[rr][c] = w[(size_t)(k0 + rr) * N + n0 + c];
    __syncthreads();
    for (int rr = r8; rr < 32; rr += 8)
        thi[(size_t)(n0 + rr) * K + k0 + c] = f2bf(tile[c][rr]);
}

// ---------------- bf16 GEMM: C[M][N] = A[M][K] * Bt[N][K]^T + bias ----------------
// BK=64; LDS rows 128B (8 x 16B chunks), chunk swizzle ^(row&7) -> conflict-free
// frag reads; gld16 staging (wave-uniform base + lane*16).
__global__ __launch_bounds__(256, 3) void gemm_bf16_k(
    const u16* __restrict__ A, const u16* __restrict__ B,
    const float* __restrict__ bias, float* __restrict__ C,
    int M, int N, int K) {
    __shared__ u16 lA[128 * 64], lB[128 * 64];
    const int t = threadIdx.x, lane = t & 63, w = t >> 6;
    const int qi = lane & 15, quad = lane >> 4;
    const int m0 = blockIdx.y * 128, n0 = blockIdx.x * 128;
    const int wm = (w >> 1) * 64, wn = (w & 1) * 64;

    floatx4 acc[4][4];
    for (int mi = 0; mi < 4; mi++)
        for (int ni = 0; ni < 4; ni++) acc[mi][ni] = (floatx4){0.f, 0.f, 0.f, 0.f};

    // staging geometry: lane -> row offset (lane>>3), swizzled chunk (lane&7)^(lane>>3)
    const int rg = lane >> 3;
    const int ce = ((lane & 7) ^ rg) * 8;  // elem offset within row
    size_t gA[4], gB[4];
    for (int g = 0; g < 4; g++) {
        int row = w * 32 + g * 8 + rg;
        gA[g] = (size_t)(m0 + row) * K + ce;
        gB[g] = (size_t)(n0 + row) * K + ce;
    }

    for (int k0 = 0; k0 < K; k0 += 64) {
        for (int g = 0; g < 4; g++) {
            gld16(A + gA[g] + k0, &lA[(w * 32 + g * 8) * 64]);
            gld16(B + gB[g] + k0, &lB[(w * 32 + g * 8) * 64]);
        }
        __syncthreads();
        short8 af[4][2], bf[4][2];
        for (int mi = 0; mi < 4; mi++) {
            int row = wm + mi * 16 + qi;
            for (int kh = 0; kh < 2; kh++)
                af[mi][kh] = *(const short8*)&lA[row * 64 + (((kh * 4 + quad) ^ (row & 7)) << 3)];
        }
        for (int ni = 0; ni < 4; ni++) {
            int row = wn + ni * 16 + qi;
            for (int kh = 0; kh < 2; kh++)
                bf[ni][kh] = *(const short8*)&lB[row * 64 + (((kh * 4 + quad) ^ (row & 7)) << 3)];
        }
        for (int mi = 0; mi < 4; mi++)
            for (int ni = 0; ni < 4; ni++) {
                acc[mi][ni] = __builtin_amdgcn_mfma_f32_16x16x32_bf16(af[mi][0], bf[ni][0], acc[mi][ni], 0, 0, 0);
                acc[mi][ni] = __builtin_amdgcn_mfma_f32_16x16x32_bf16(af[mi][1], bf[ni][1], acc[mi][ni], 0, 0, 0);
            }
        __syncthreads();
    }
    for (int mi = 0; mi < 4; mi++)
        for (int ni = 0; ni < 4; ni++) {
            int col = n0 + wn + ni * 16 + qi;
            int rowb = m0 + wm + mi * 16 + quad * 4;
            float b = bias[col];
            for (int r = 0; r < 4; r++)
                C[(size_t)(rowb + r) * N + col] = acc[mi][ni][r] + b;
        }
}

// ---------------- pack: rope+scale Q,K -> swizzled [h][s][96]; V -> swizzled Vt[h][80][SEQ] ----------------
__global__ void pack_qkv_k(const float* __restrict__ qkv, const float* __restrict__ cosb,
                           const float* __restrict__ sinb,
                           u16* __restrict__ Qs, u16* __restrict__ Ks, u16* __restrict__ Vs) {
    __shared__ float lv[80 * 65];
    const int t = threadIdx.x;
    const int h = blockIdx.y, s0 = blockIdx.x * 64;
    const float scale = 0.11180339887498949f;  // 80^-0.5

    for (int i = t; i < 64 * 40; i += 256) {
        int rl = i / 40, j = i % 40;
        int s = s0 + rl;
        float c = cosb[s * 40 + j], sn = sinb[s * 40 + j];
        const float* qb = qkv + (size_t)s * NQKV + h * HD;
        float q1 = qb[j], q2 = qb[j + 40];
        size_t base = (size_t)(h * SEQ + s) * 96;
        int j2 = j + 40;
        size_t o1 = base + swz_qk(j >> 3, s) * 8 + (j & 7);
        size_t o2 = base + swz_qk(j2 >> 3, s) * 8 + (j2 & 7);
        Qs[o1] = f2bf((q1 * c - q2 * sn) * scale);
        Qs[o2] = f2bf((q2 * c + q1 * sn) * scale);
        const float* kb = qb + HID;
        float k1 = kb[j], k2 = kb[j + 40];
        Ks[o1] = f2bf(k1 * c - k2 * sn);
        Ks[o2] = f2bf(k2 * c + k1 * sn);
    }
    for (int i = t; i < 64 * 16; i += 256) {  // zero-pad logical elems 80..95
        int rl = i / 16, jj = 80 + i % 16;
        int s = s0 + rl;
        size_t o = (size_t)(h * SEQ + s) * 96 + swz_qk(jj >> 3, s) * 8 + (jj & 7);
        Qs[o] = 0;
        Ks[o] = 0;
    }
    for (int i = t; i < 64 * 80; i += 256) {
        int rl = i / 80, d = i % 80;
        lv[d * 65 + rl] = qkv[(size_t)(s0 + rl) * NQKV + 2 * HID + h * HD + d];
    }
    __syncthreads();
    for (int i = t; i < 80 * 64; i += 256) {
        int d = i / 64, c2l = i % 64;
        int pc = ((c2l >> 3) ^ (d & 7));
        Vs[((size_t)h * HD + d) * SEQ + s0 + pc * 8 + (c2l & 7)] = f2bf(lv[d * 65 + c2l]);
    }
}

// ---------------- flash attention: QT=128, key-split 2, no-max softmax ----------------
__global__ __launch_bounds__(256, 3) void attn_k(
    const u16* __restrict__ Qs, const u16* __restrict__ Ks, const u16* __restrict__ Vs,
    float* __restrict__ Op, float* __restrict__ lp) {
    __shared__ u16 kbuf[2][6144];  // 12KB each; [0..1] doubles as 24KB Q staging
    __shared__ u16 vbuf[2][5120];  // 10KB each
    __shared__ u16 pls[4][1024];   // 2KB per wave (wave-private P transpose)

    const int t = threadIdx.x, lane = t & 63, w = t >> 6;
    const int qi = lane & 15, quad = lane >> 4;
    const int h = blockIdx.y, q0 = blockIdx.x * 128, ksp = blockIdx.z;
    const int kc0 = ksp * (SEQ / 2);
    u16* const kflat = &kbuf[0][0];

    // ---- stage Q (128 rows x 192B, contiguous) ----
    {
        const u16* Qt = Qs + (size_t)(h * SEQ + q0) * 96;
        for (int j = 0; j < 6; j++) {
            int o = (w * 6 + j) * 512;
            gld16(Qt + o + lane * 8, kflat + o);
        }
    }
    __syncthreads();
    short8 bq[2][3];
    for (int qg = 0; qg < 2; qg++) {
        int row = w * 32 + qg * 16 + qi;
        for (int k3 = 0; k3 < 3; k3++) {
            int p = (k3 < 2) ? ((4 * k3 + quad) ^ (qi & 7)) : (8 + (quad ^ (qi & 3)));
            bq[qg][k3] = *(const short8*)&kflat[(row * 12 + p) * 8];
        }
    }
    __syncthreads();

    float l_lane[2] = {0.f, 0.f};
    floatx4 acco[2][5];
    for (int qg = 0; qg < 2; qg++)
        for (int dt = 0; dt < 5; dt++) acco[qg][dt] = (floatx4){0.f, 0.f, 0.f, 0.f};

    auto stage = [&](int it, int buf) {
        int kc = kc0 + it * 64;
        const u16* Kt = Ks + (size_t)(h * SEQ + kc) * 96;
        for (int j = 0; j < 3; j++) {
            int o = (w * 3 + j) * 512;
            gld16(Kt + o + lane * 8, &kbuf[buf][o]);
        }
        const u16* Vt = Vs + (size_t)h * HD * SEQ + kc;
        for (int i = w; i < 10; i += 4) {
            int p16 = i * 64 + lane;
            int d = p16 >> 3, pc = p16 & 7;
            gld16(Vt + (size_t)d * SEQ + pc * 8, &vbuf[buf][i * 512]);
        }
    };
    stage(0, 0);
    __syncthreads();

    const int NT = (SEQ / 2) / 64;  // 24
    char* const myp = (char*)&pls[w][0];
    for (int it = 0; it < NT; it++) {
        int cur = it & 1;
        if (it + 1 < NT) stage(it + 1, cur ^ 1);
        const u16* kb = &kbuf[cur][0];
        const u16* vb = &vbuf[cur][0];
        for (int c2 = 0; c2 < 2; c2++) {
            for (int ktl = 0; ktl < 2; ktl++) {
                int kt = c2 * 2 + ktl;
                int arow = kt * 16 + qi;
                short8 ak[3];
                for (int k3 = 0; k3 < 3; k3++) {
                    int p = (k3 < 2) ? ((4 * k3 + quad) ^ (qi & 7)) : (8 + (quad ^ (qi & 3)));
                    ak[k3] = *(const short8*)&kb[(arow * 12 + p) * 8];
                }
                for (int qg = 0; qg < 2; qg++) {
                    floatx4 s = (floatx4){0.f, 0.f, 0.f, 0.f};
                    s = __builtin_amdgcn_mfma_f32_16x16x32_bf16(ak[0], bq[qg][0], s, 0, 0, 0);
                    s = __builtin_amdgcn_mfma_f32_16x16x32_bf16(ak[1], bq[qg][1], s, 0, 0, 0);
                    s = __builtin_amdgcn_mfma_f32_16x16x32_bf16(ak[2], bq[qg][2], s, 0, 0, 0);
                    float e0 = __expf(s[0]), e1 = __expf(s[1]);
                    float e2 = __expf(s[2]), e3 = __expf(s[3]);
                    l_lane[qg] += (e0 + e1) + (e2 + e3);
                    uint2 pk;
                    pk.x = pack2bf(e0, e1);
                    pk.y = pack2bf(e2, e3);
                    int u = 2 * ktl + (quad >> 1);
                    *(uint2*)(myp + qg * 1024 + qi * 64 + ((u ^ (qi & 3)) << 4) + ((quad & 1) << 3)) = pk;
                }
            }
            short8 bp0 = *(const short8*)(myp + qi * 64 + ((quad ^ (qi & 3)) << 4));
            short8 bp1 = *(const short8*)(myp + 1024 + qi * 64 + ((quad ^ (qi & 3)) << 4));
            int pv = (4 * c2 + quad) ^ (qi & 7);
            for (int dt = 0; dt < 5; dt++) {
                short8 av = *(const short8*)&vb[((dt * 16 + qi) * 8 + pv) * 8];
                acco[0][dt] = __builtin_amdgcn_mfma_f32_16x16x32_bf16(av, bp0, acco[0][dt], 0, 0, 0);
                acco[1][dt] = __builtin_amdgcn_mfma_f32_16x16x32_bf16(av, bp1, acco[1][dt], 0, 0, 0);
            }
        }
        __syncthreads();
    }

    for (int qg = 0; qg < 2; qg++) {
        float lq = l_lane[qg];
        lq += __shfl_xor(lq, 16);
        lq += __shfl_xor(lq, 32);
        int q = q0 + w * 32 + qg * 16 + qi;
        if (quad == 0) lp[(size_t)(ksp * NH + h) * SEQ + q] = lq;
        for (int dt = 0; dt < 5; dt++)
            for (int r = 0; r < 4; r++) {
                int d = dt * 16 + quad * 4 + r;
                Op[((size_t)(ksp * NH + h) * HD + d) * SEQ + q] = acco[qg][dt][r];
            }
    }
}

// ---------------- merge key-split partials -> att bf16 [SEQ][HID] ----------------
__global__ void merge_k(const float* __restrict__ Op, const float* __restrict__ lp,
                        u16* __restrict__ att) {
    __shared__ float ls[HD * 65];
    __shared__ float li[64];
    const int t = threadIdx.x;
    const int h = blockIdx.y, q0 = blockIdx.x * 64;
    for (int i = t; i < HD * 64; i += 256) {
        int d = i / 64, ql = i % 64;
        size_t a0 = ((size_t)h * HD + d) * SEQ + q0 + ql;
        size_t a1 = ((size_t)(NH + h) * HD + d) * SEQ + q0 + ql;
        ls[d * 65 + ql] = Op[a0] + Op[a1];
    }
    if (t < 64)
        li[t] = 1.0f / (lp[(size_t)h * SEQ + q0 + t] + lp[(size_t)(NH + h) * SEQ + q0 + t]);
    __syncthreads();
    for (int i = t; i < 64 * HD; i += 256) {
        int ql = i / HD, d = i % HD;
        att[(size_t)(q0 + ql) * HID + h * HD + d] = f2bf(ls[d * 65 + ql] * li[ql]);
    }
}

extern "C" void kernel_launch(void* const* d_in, const int* in_sizes, int n_in,
                              void* d_out, int out_size, void* d_ws, size_t ws_size,
                              hipStream_t stream) {
    const float* hs   = (const float*)d_in[0];
    const int*   pos  = (const int*)d_in[1];
    const float* qkvw = (const float*)d_in[2];
    const float* qkvb = (const float*)d_in[3];
    const float* ow   = (const float*)d_in[4];
    const float* ob   = (const float*)d_in[5];
    float* out = (float*)d_out;

    char* p = (char*)d_ws;
    auto alloc = [&](size_t bytes) {
        char* r = p;
        p += (bytes + 255) & ~(size_t)255;
        return r;
    };
    float* cosb = (float*)alloc((size_t)SEQ * 40 * 4);
    float* sinb = (float*)alloc((size_t)SEQ * 40 * 4);
    u16* owT = (u16*)alloc((size_t)HID * HID * 2);
    // pool1: phase A = hidden bf16 + qkv_w^T bf16; phase B = Qs + Ks (aliased)
    char* pool1 = alloc(18874368 + 9437184);
    u16* hH = (u16*)pool1;
    u16* wT = (u16*)(pool1 + 7864320);
    u16* Qs = (u16*)pool1;                    // phase B
    u16* Ks = (u16*)(pool1 + 9437184);
    // pool2: phase A = qkv f32; phase B = att bf16 + Op partials + l partials
    char* pool2 = alloc((size_t)SEQ * NQKV * 4);
    float* qkv_s = (float*)pool2;
    u16* att  = (u16*)pool2;
    float* Op = (float*)(pool2 + 7864320);
    float* lp = (float*)(pool2 + 39321600);
    u16* Vs = (u16*)alloc((size_t)NH * HD * SEQ * 2);

    hipLaunchKernelGGL(rope_tables_k, dim3(SEQ), dim3(64), 0, stream, pos, cosb, sinb);
    hipLaunchKernelGGL(cast_bf16_k, dim3((SEQ * HID + 255) / 256), dim3(256), 0, stream,
                       hs, hH, SEQ * HID);
    hipLaunchKernelGGL(transpose_cast_k, dim3(NQKV / 32, HID / 32), dim3(256), 0, stream,
                       qkvw, wT, HID, NQKV);
    hipLaunchKernelGGL(transpose_cast_k, dim3(HID / 32, HID / 32), dim3(256), 0, stream,
                       ow, owT, HID, HID);
    hipLaunchKernelGGL(gemm_bf16_k, dim3(NQKV / 128, SEQ / 128), dim3(256), 0, stream,
                       hH, wT, qkvb, qkv_s, SEQ, NQKV, HID);
    hipLaunchKernelGGL(pack_qkv_k, dim3(SEQ / 64, NH), dim3(256), 0, stream,
                       qkv_s, cosb, sinb, Qs, Ks, Vs);
    hipLaunchKernelGGL(attn_k, dim3(SEQ / 128, NH, 2), dim3(256), 0, stream,
                       Qs, Ks, Vs, Op, lp);
    hipLaunchKernelGGL(merge_k, dim3(SEQ / 64, NH), dim3(256), 0, stream, Op, lp, att);
    hipLaunchKernelGGL(gemm_bf16_k, dim3(HID / 128, SEQ / 128), dim3(256), 0, stream,
                       att, owT, ob, out, SEQ, HID, HID);
}

// Round 5
// 248.779 us; speedup vs baseline: 2.5115x; 1.0325x over previous
//
#include <hip/hip_runtime.h>

#define SEQ  3072
#define HID  1280
#define NH   16
#define HD   80
#define NQKV 3840

typedef unsigned short u16;
typedef unsigned int u32;
typedef __attribute__((ext_vector_type(8))) short short8;
typedef __attribute__((ext_vector_type(4))) float floatx4;

__device__ __forceinline__ u16 f2bf(float x) {
    u32 u = __float_as_uint(x);
    u += 0x7fffu + ((u >> 16) & 1u);
    return (u16)(u >> 16);
}
__device__ __forceinline__ u32 packrne(float a, float b) {
    return (u32)f2bf(a) | ((u32)f2bf(b) << 16);
}

typedef const __attribute__((address_space(1))) unsigned int* gp1_t;
typedef __attribute__((address_space(3))) unsigned int* lp3_t;
__device__ __forceinline__ void gld16(const void* g, void* l) {
    __builtin_amdgcn_global_load_lds((gp1_t)g, (lp3_t)l, 16, 0, 0);
}

// swizzled 16B-chunk position for Q/K rows (12 chunks / 192B):
// main chunks 0..7: ^ (r&7); tail 8..11: ^ ((r>>1)&3)  [slot-spread proof in journal]
__device__ __forceinline__ int swz_qk(int c, int r) {
    return (c < 8) ? (c ^ (r & 7)) : (8 + ((c - 8) ^ ((r >> 1) & 3)));
}

// ---------------- rope tables: cos/sin [SEQ][40] ----------------
__global__ void rope_tables_k(const int* __restrict__ pos, float* __restrict__ cosb,
                              float* __restrict__ sinb) {
    int s = blockIdx.x;
    int j = threadIdx.x;
    if (j >= 40) return;
    float p = (float)((j < 20) ? pos[s * 2] : pos[s * 2 + 1]);
    int i = (j < 20) ? j : j - 20;
    float inv = powf(10000.0f, -(float)i / 20.0f);
    float a = p * inv;
    cosb[s * 40 + j] = cosf(a);
    sinb[s * 40 + j] = sinf(a);
}

// ---------------- cast f32 -> bf16 ----------------
__global__ void cast_bf16_k(const float* __restrict__ x, u16* __restrict__ hi, int n) {
    int i = blockIdx.x * 256 + threadIdx.x;
    if (i >= n) return;
    hi[i] = f2bf(x[i]);
}

// ---------------- transpose + cast: w[K][N] -> t[N][K] bf16 ----------------
__global__ void transpose_cast_k(const float* __restrict__ w, u16* __restrict__ thi,
                                 int K, int N) {
    __shared__ float tile[32][33];
    int n0 = blockIdx.x * 32, k0 = blockIdx.y * 32;
    int c = threadIdx.x & 31, r8 = threadIdx.x >> 5;
    for (int rr = r8; rr < 32; rr += 8)
        tile[rr][c] = w[(size_t)(k0 + rr) * N + n0 + c];
    __syncthreads();
    for (int rr = r8; rr < 32; rr += 8)
        thi[(size_t)(n0 + rr) * K + k0 + c] = f2bf(tile[c][rr]);
}

// ---------------- bf16 GEMM: C[M][N] = A[M][K] * Bt[N][K]^T + bias ----------------
__global__ __launch_bounds__(256, 3) void gemm_bf16_k(
    const u16* __restrict__ A, const u16* __restrict__ B,
    const float* __restrict__ bias, float* __restrict__ C,
    int M, int N, int K) {
    __shared__ u16 lA[128 * 64], lB[128 * 64];
    const int t = threadIdx.x, lane = t & 63, w = t >> 6;
    const int qi = lane & 15, quad = lane >> 4;
    const int m0 = blockIdx.y * 128, n0 = blockIdx.x * 128;
    const int wm = (w >> 1) * 64, wn = (w & 1) * 64;

    floatx4 acc[4][4];
    for (int mi = 0; mi < 4; mi++)
        for (int ni = 0; ni < 4; ni++) acc[mi][ni] = (floatx4){0.f, 0.f, 0.f, 0.f};

    const int rg = lane >> 3;
    const int ce = ((lane & 7) ^ rg) * 8;
    size_t gA[4], gB[4];
    for (int g = 0; g < 4; g++) {
        int row = w * 32 + g * 8 + rg;
        gA[g] = (size_t)(m0 + row) * K + ce;
        gB[g] = (size_t)(n0 + row) * K + ce;
    }

    for (int k0 = 0; k0 < K; k0 += 64) {
        for (int g = 0; g < 4; g++) {
            gld16(A + gA[g] + k0, &lA[(w * 32 + g * 8) * 64]);
            gld16(B + gB[g] + k0, &lB[(w * 32 + g * 8) * 64]);
        }
        __syncthreads();
        short8 af[4][2], bf[4][2];
        for (int mi = 0; mi < 4; mi++) {
            int row = wm + mi * 16 + qi;
            for (int kh = 0; kh < 2; kh++)
                af[mi][kh] = *(const short8*)&lA[row * 64 + (((kh * 4 + quad) ^ (row & 7)) << 3)];
        }
        for (int ni = 0; ni < 4; ni++) {
            int row = wn + ni * 16 + qi;
            for (int kh = 0; kh < 2; kh++)
                bf[ni][kh] = *(const short8*)&lB[row * 64 + (((kh * 4 + quad) ^ (row & 7)) << 3)];
        }
        for (int mi = 0; mi < 4; mi++)
            for (int ni = 0; ni < 4; ni++) {
                acc[mi][ni] = __builtin_amdgcn_mfma_f32_16x16x32_bf16(af[mi][0], bf[ni][0], acc[mi][ni], 0, 0, 0);
                acc[mi][ni] = __builtin_amdgcn_mfma_f32_16x16x32_bf16(af[mi][1], bf[ni][1], acc[mi][ni], 0, 0, 0);
            }
        __syncthreads();
    }
    for (int mi = 0; mi < 4; mi++)
        for (int ni = 0; ni < 4; ni++) {
            int col = n0 + wn + ni * 16 + qi;
            int rowb = m0 + wm + mi * 16 + quad * 4;
            float b = bias[col];
            for (int r = 0; r < 4; r++)
                C[(size_t)(rowb + r) * N + col] = acc[mi][ni][r] + b;
        }
}

// ---------------- pack: rope Q (x scale x log2e), K -> swizzled [h][s][96]; V -> swizzled Vt ----------------
__global__ void pack_qkv_k(const float* __restrict__ qkv, const float* __restrict__ cosb,
                           const float* __restrict__ sinb,
                           u16* __restrict__ Qs, u16* __restrict__ Ks, u16* __restrict__ Vs) {
    __shared__ float lv[80 * 65];
    const int t = threadIdx.x;
    const int h = blockIdx.y, s0 = blockIdx.x * 64;
    const float qsc = 0.11180339887498949f * 1.4426950408889634f;  // 80^-0.5 * log2(e)

    for (int i = t; i < 64 * 10; i += 256) {
        int rl = i / 10, jg = i % 10;
        int s = s0 + rl, j = jg * 4;
        const float4 cc = *(const float4*)&cosb[s * 40 + j];
        const float4 ss = *(const float4*)&sinb[s * 40 + j];
        const float* qb = qkv + (size_t)s * NQKV + h * HD;
        const float4 q1 = *(const float4*)&qb[j];
        const float4 q2 = *(const float4*)&qb[j + 40];
        const float* kb = qb + HID;
        const float4 k1 = *(const float4*)&kb[j];
        const float4 k2 = *(const float4*)&kb[j + 40];
        uint2 qo1, qo2, ko1, ko2;
        qo1.x = packrne((q1.x * cc.x - q2.x * ss.x) * qsc, (q1.y * cc.y - q2.y * ss.y) * qsc);
        qo1.y = packrne((q1.z * cc.z - q2.z * ss.z) * qsc, (q1.w * cc.w - q2.w * ss.w) * qsc);
        qo2.x = packrne((q2.x * cc.x + q1.x * ss.x) * qsc, (q2.y * cc.y + q1.y * ss.y) * qsc);
        qo2.y = packrne((q2.z * cc.z + q1.z * ss.z) * qsc, (q2.w * cc.w + q1.w * ss.w) * qsc);
        ko1.x = packrne(k1.x * cc.x - k2.x * ss.x, k1.y * cc.y - k2.y * ss.y);
        ko1.y = packrne(k1.z * cc.z - k2.z * ss.z, k1.w * cc.w - k2.w * ss.w);
        ko2.x = packrne(k2.x * cc.x + k1.x * ss.x, k2.y * cc.y + k1.y * ss.y);
        ko2.y = packrne(k2.z * cc.z + k1.z * ss.z, k2.w * cc.w + k1.w * ss.w);
        size_t base = (size_t)(h * SEQ + s) * 96;
        int c0 = j >> 3, sub0 = j & 7;
        int c1 = (j + 40) >> 3, sub1 = (j + 40) & 7;
        int p0 = swz_qk(c0, s);
        int p1 = swz_qk(c1, s);
        *(uint2*)&Qs[base + p0 * 8 + sub0] = qo1;
        *(uint2*)&Qs[base + p1 * 8 + sub1] = qo2;
        *(uint2*)&Ks[base + p0 * 8 + sub0] = ko1;
        *(uint2*)&Ks[base + p1 * 8 + sub1] = ko2;
    }
    for (int i = t; i < 64 * 2; i += 256) {  // zero tail chunks 10,11 (dims 80..95)
        int rl = i >> 1, cz = 10 + (i & 1);
        int s = s0 + rl;
        int pz = swz_qk(cz, s);
        size_t base = (size_t)(h * SEQ + s) * 96;
        *(uint4*)&Qs[base + pz * 8] = (uint4){0, 0, 0, 0};
        *(uint4*)&Ks[base + pz * 8] = (uint4){0, 0, 0, 0};
    }
    for (int i = t; i < 64 * 80; i += 256) {
        int rl = i / 80, d = i % 80;
        lv[d * 65 + rl] = qkv[(size_t)(s0 + rl) * NQKV + 2 * HID + h * HD + d];
    }
    __syncthreads();
    for (int i = t; i < 80 * 16; i += 256) {
        int d = i / 16, g = i % 16;
        int c2l = g * 4;
        float v0 = lv[d * 65 + c2l], v1 = lv[d * 65 + c2l + 1];
        float v2 = lv[d * 65 + c2l + 2], v3 = lv[d * 65 + c2l + 3];
        int pc = (g >> 1) ^ (d & 7);
        uint2 o;
        o.x = packrne(v0, v1);
        o.y = packrne(v2, v3);
        *(uint2*)&Vs[((size_t)h * HD + d) * SEQ + s0 + pc * 8 + (g & 1) * 4] = o;
    }
}

// ---------------- flash attention: QT=128, key-split 2, no-max exp2 softmax ----------------
__global__ __launch_bounds__(256, 3) void attn_k(
    const u16* __restrict__ Qs, const u16* __restrict__ Ks, const u16* __restrict__ Vs,
    float* __restrict__ Op, float* __restrict__ lp) {
    __shared__ u16 kbuf[2][6144];  // 12KB each; pair doubles as 24KB Q staging
    __shared__ u16 vbuf[2][5120];  // 10KB each
    __shared__ u16 pls[4][1024];   // per-wave 16q x 64k (2 qg interleaved), 128B rows

    const int t = threadIdx.x, lane = t & 63, w = t >> 6;
    const int qi = lane & 15, quad = lane >> 4;
    const int h = blockIdx.y, q0 = blockIdx.x * 128, ksp = blockIdx.z;
    const int kc0 = ksp * (SEQ / 2);
    u16* const kflat = &kbuf[0][0];

    {
        const u16* Qt = Qs + (size_t)(h * SEQ + q0) * 96;
        for (int j = 0; j < 6; j++) {
            int o = (w * 6 + j) * 512;
            gld16(Qt + o + lane * 8, kflat + o);
        }
    }
    __syncthreads();
    short8 bq[2][3];
    for (int qg = 0; qg < 2; qg++) {
        int row = w * 32 + qg * 16 + qi;
        for (int k3 = 0; k3 < 3; k3++) {
            int p = (k3 < 2) ? ((4 * k3 + quad) ^ (qi & 7)) : (8 + (quad ^ ((qi >> 1) & 3)));
            bq[qg][k3] = *(const short8*)&kflat[(row * 12 + p) * 8];
        }
    }
    __syncthreads();

    float l_lane[2] = {0.f, 0.f};
    floatx4 acco[2][5];
    for (int qg = 0; qg < 2; qg++)
        for (int dt = 0; dt < 5; dt++) acco[qg][dt] = (floatx4){0.f, 0.f, 0.f, 0.f};

    auto stage = [&](int it, int buf) {
        int kc = kc0 + it * 64;
        const u16* Kt = Ks + (size_t)(h * SEQ + kc) * 96;
        for (int j = 0; j < 3; j++) {
            int o = (w * 3 + j) * 512;
            gld16(Kt + o + lane * 8, &kbuf[buf][o]);
        }
        const u16* Vt = Vs + (size_t)h * HD * SEQ + kc;
        for (int i = w; i < 10; i += 4) {
            int p16 = i * 64 + lane;
            int d = p16 >> 3, pc = p16 & 7;
            gld16(Vt + (size_t)d * SEQ + pc * 8, &vbuf[buf][i * 512]);
        }
    };
    stage(0, 0);
    __syncthreads();

    const int NT = (SEQ / 2) / 64;  // 24
    char* const myp = (char*)&pls[w][0];
    for (int it = 0; it < NT; it++) {
        int cur = it & 1;
        if (it + 1 < NT) stage(it + 1, cur ^ 1);
        const u16* kb = &kbuf[cur][0];
        const u16* vb = &vbuf[cur][0];
        for (int c2 = 0; c2 < 2; c2++) {
            for (int ktl = 0; ktl < 2; ktl++) {
                int kt = c2 * 2 + ktl;
                int arow = kt * 16 + qi;
                short8 ak[3];
                for (int k3 = 0; k3 < 3; k3++) {
                    int p = (k3 < 2) ? ((4 * k3 + quad) ^ (qi & 7)) : (8 + (quad ^ ((qi >> 1) & 3)));
                    ak[k3] = *(const short8*)&kb[(arow * 12 + p) * 8];
                }
                for (int qg = 0; qg < 2; qg++) {
                    floatx4 s = (floatx4){0.f, 0.f, 0.f, 0.f};
                    s = __builtin_amdgcn_mfma_f32_16x16x32_bf16(ak[0], bq[qg][0], s, 0, 0, 0);
                    s = __builtin_amdgcn_mfma_f32_16x16x32_bf16(ak[1], bq[qg][1], s, 0, 0, 0);
                    s = __builtin_amdgcn_mfma_f32_16x16x32_bf16(ak[2], bq[qg][2], s, 0, 0, 0);
                    float e0 = __builtin_amdgcn_exp2f(s[0]);
                    float e1 = __builtin_amdgcn_exp2f(s[1]);
                    float e2 = __builtin_amdgcn_exp2f(s[2]);
                    float e3 = __builtin_amdgcn_exp2f(s[3]);
                    l_lane[qg] += (e0 + e1) + (e2 + e3);
                    uint2 pk;  // truncating bf16x2 pack via v_perm (1 instr each)
                    pk.x = __builtin_amdgcn_perm(__float_as_uint(e1), __float_as_uint(e0), 0x07060302u);
                    pk.y = __builtin_amdgcn_perm(__float_as_uint(e3), __float_as_uint(e2), 0x07060302u);
                    int chunk = qg * 4 + 2 * ktl + (quad >> 1);
                    *(uint2*)(myp + qi * 128 + ((chunk ^ (qi & 7)) << 4) + ((quad & 1) << 3)) = pk;
                }
            }
            short8 bp0 = *(const short8*)(myp + qi * 128 + (((quad) ^ (qi & 7)) << 4));
            short8 bp1 = *(const short8*)(myp + qi * 128 + (((4 + quad) ^ (qi & 7)) << 4));
            int pv = (4 * c2 + quad) ^ (qi & 7);
            for (int dt = 0; dt < 5; dt++) {
                short8 av = *(const short8*)&vb[((dt * 16 + qi) * 8 + pv) * 8];
                acco[0][dt] = __builtin_amdgcn_mfma_f32_16x16x32_bf16(av, bp0, acco[0][dt], 0, 0, 0);
                acco[1][dt] = __builtin_amdgcn_mfma_f32_16x16x32_bf16(av, bp1, acco[1][dt], 0, 0, 0);
            }
        }
        __syncthreads();
    }

    for (int qg = 0; qg < 2; qg++) {
        float lq = l_lane[qg];
        lq += __shfl_xor(lq, 16);
        lq += __shfl_xor(lq, 32);
        int q = q0 + w * 32 + qg * 16 + qi;
        if (quad == 0) lp[(size_t)(ksp * NH + h) * SEQ + q] = lq;
        for (int dt = 0; dt < 5; dt++)
            for (int r = 0; r < 4; r++) {
                int d = dt * 16 + quad * 4 + r;
                Op[((size_t)(ksp * NH + h) * HD + d) * SEQ + q] = acco[qg][dt][r];
            }
    }
}

// ---------------- merge key-split partials -> att bf16 [SEQ][HID] ----------------
__global__ void merge_k(const float* __restrict__ Op, const float* __restrict__ lp,
                        u16* __restrict__ att) {
    __shared__ float ls[HD * 65];
    __shared__ float li[64];
    const int t = threadIdx.x;
    const int h = blockIdx.y, q0 = blockIdx.x * 64;
    for (int i = t; i < HD * 16; i += 256) {
        int d = i / 16, g = i % 16;
        size_t a0 = ((size_t)h * HD + d) * SEQ + q0 + g * 4;
        size_t a1 = ((size_t)(NH + h) * HD + d) * SEQ + q0 + g * 4;
        const float4 v0 = *(const float4*)&Op[a0];
        const float4 v1 = *(const float4*)&Op[a1];
        ls[d * 65 + g * 4 + 0] = v0.x + v1.x;
        ls[d * 65 + g * 4 + 1] = v0.y + v1.y;
        ls[d * 65 + g * 4 + 2] = v0.z + v1.z;
        ls[d * 65 + g * 4 + 3] = v0.w + v1.w;
    }
    if (t < 64)
        li[t] = 1.0f / (lp[(size_t)h * SEQ + q0 + t] + lp[(size_t)(NH + h) * SEQ + q0 + t]);
    __syncthreads();
    for (int i = t; i < 64 * 40; i += 256) {
        int ql = i / 40, dg = i % 40;
        int d0 = dg * 2;
        float s = li[ql];
        u32 o = packrne(ls[d0 * 65 + ql] * s, ls[(d0 + 1) * 65 + ql] * s);
        *(u32*)&att[(size_t)(q0 + ql) * HID + h * HD + d0] = o;
    }
}

extern "C" void kernel_launch(void* const* d_in, const int* in_sizes, int n_in,
                              void* d_out, int out_size, void* d_ws, size_t ws_size,
                              hipStream_t stream) {
    const float* hs   = (const float*)d_in[0];
    const int*   pos  = (const int*)d_in[1];
    const float* qkvw = (const float*)d_in[2];
    const float* qkvb = (const float*)d_in[3];
    const float* ow   = (const float*)d_in[4];
    const float* ob   = (const float*)d_in[5];
    float* out = (float*)d_out;

    char* p = (char*)d_ws;
    auto alloc = [&](size_t bytes) {
        char* r = p;
        p += (bytes + 255) & ~(size_t)255;
        return r;
    };
    float* cosb = (float*)alloc((size_t)SEQ * 40 * 4);
    float* sinb = (float*)alloc((size_t)SEQ * 40 * 4);
    u16* owT = (u16*)alloc((size_t)HID * HID * 2);
    // pool1: phase A = hidden bf16 + qkv_w^T bf16; phase B = Qs + Ks (aliased)
    char* pool1 = alloc(18874368 + 9437184);
    u16* hH = (u16*)pool1;
    u16* wT = (u16*)(pool1 + 7864320);
    u16* Qs = (u16*)pool1;                    // phase B
    u16* Ks = (u16*)(pool1 + 9437184);
    // pool2: phase A = qkv f32; phase B = att bf16 + Op partials + l partials
    char* pool2 = alloc((size_t)SEQ * NQKV * 4);
    float* qkv_s = (float*)pool2;
    u16* att  = (u16*)pool2;
    float* Op = (float*)(pool2 + 7864320);
    float* lp = (float*)(pool2 + 39321600);
    u16* Vs = (u16*)alloc((size_t)NH * HD * SEQ * 2);

    hipLaunchKernelGGL(rope_tables_k, dim3(SEQ), dim3(64), 0, stream, pos, cosb, sinb);
    hipLaunchKernelGGL(cast_bf16_k, dim3((SEQ * HID + 255) / 256), dim3(256), 0, stream,
                       hs, hH, SEQ * HID);
    hipLaunchKernelGGL(transpose_cast_k, dim3(NQKV / 32, HID / 32), dim3(256), 0, stream,
                       qkvw, wT, HID, NQKV);
    hipLaunchKernelGGL(transpose_cast_k, dim3(HID / 32, HID / 32), dim3(256), 0, stream,
                       ow, owT, HID, HID);
    hipLaunchKernelGGL(gemm_bf16_k, dim3(NQKV / 128, SEQ / 128), dim3(256), 0, stream,
                       hH, wT, qkvb, qkv_s, SEQ, NQKV, HID);
    hipLaunchKernelGGL(pack_qkv_k, dim3(SEQ / 64, NH), dim3(256), 0, stream,
                       qkv_s, cosb, sinb, Qs, Ks, Vs);
    hipLaunchKernelGGL(attn_k, dim3(SEQ / 128, NH, 2), dim3(256), 0, stream,
                       Qs, Ks, Vs, Op, lp);
    hipLaunchKernelGGL(merge_k, dim3(SEQ / 64, NH), dim3(256), 0, stream, Op, lp, att);
    hipLaunchKernelGGL(gemm_bf16_k, dim3(HID / 128, SEQ / 128), dim3(256), 0, stream,
                       att, owT, ob, out, SEQ, HID, HID);
}